// Round 3
// baseline (568.615 us; speedup 1.0000x reference)
//
#include <hip/hip_runtime.h>
#include <hip/hip_bf16.h>
#include <math.h>

// SpKBGAT: N=50000, D=200, R=500, NHID=100, H=2, OD=200, E=150000, ENH=30000.
// R11: gathers still latency-bound (VALU 45%, HBM 13%). (1) head-interleaved
// pB/rpf2/srel2 so each dual-head read is one 4-8B load, (2) 4-wide predicated
// edge blocks (MLP=4, E[chains] 2.0->1.2), (3) branchless r2, 32-bit offsets.
#define DD   200
#define NHID 100
#define OD   200
#define KP   224   // padded K (7 chunks of 32)
#define PBS  224   // padded row stride (bf16) for pB / x1A2: 448 B
                   // pB: [k][h0,h1] pairs k<100; bytes 400..407 = s2 floats
                   // x1A2: 200 contiguous feats; byte 400 = s2 float
#define LDSW 40    // LDS row stride in shorts (80 B)

typedef __attribute__((ext_vector_type(8))) short short8;
typedef __attribute__((ext_vector_type(4))) float f32x4;

static inline int cdiv(int a, int b) { return (a + b - 1) / b; }

__device__ inline float toF(float x) { return x; }
__device__ inline float toF(__hip_bfloat16 x) { return __bfloat162float(x); }
__device__ inline void storeC(float v, float* p) { *p = v; }
__device__ inline void storeC(float v, __hip_bfloat16* p) { *p = __float2bfloat16(v); }
__device__ inline short bf16s(float f) {
    __hip_bfloat16 h = __float2bfloat16(f);
    short s; __builtin_memcpy(&s, &h, 2); return s;
}
__device__ inline float bfLo(unsigned u) { return __uint_as_float(u << 16); }
__device__ inline float bfHi(unsigned u) { return __uint_as_float(u & 0xFFFF0000u); }

// -------- per-row inverse L2 norm (f32), wave per row --------
__global__ __launch_bounds__(256)
void rownorm_inv_k(const float* __restrict__ in, float* __restrict__ sc, int M, int Dd)
{
    int wave = (blockIdx.x * blockDim.x + threadIdx.x) >> 6;
    int lane = threadIdx.x & 63;
    if (wave >= M) return;
    float ss = 0.f;
    for (int k = lane; k < Dd; k += 64) {
        float x = in[(size_t)wave * Dd + k];
        ss += x * x;
    }
    for (int o = 32; o > 0; o >>= 1) ss += __shfl_down(ss, o);
    if (lane == 0) sc[wave] = 1.f / fmaxf(sqrtf(ss), 1e-12f);
}

// -------- B-panel prep: bf16 [col][KP], zero-padded --------
__global__ void prep_bt_l1(const float* __restrict__ ah, __hip_bfloat16* __restrict__ Bt)
{
    int c = blockIdx.x, k = threadIdx.x;
    if (k >= KP) return;
    int seg = c / 100, idx = c - seg * 100;
    int h = seg & 1, off = (seg >> 1) * 200;
    float v = (k < 200) ? ah[(size_t)(h * 100 + idx) * 600 + off + k] : 0.f;
    Bt[(size_t)c * KP + k] = __float2bfloat16(v);
}
__global__ void prep_bt_l2(const float* __restrict__ ao, __hip_bfloat16* __restrict__ Bt)
{
    int c = blockIdx.x, k = threadIdx.x;
    if (k >= KP) return;
    int row = (c < 200) ? c : c - 200;
    int off = (c < 200) ? 0 : 200;
    float v = (k < 200) ? ao[(size_t)row * 600 + off + k] : 0.f;
    Bt[(size_t)c * KP + k] = __float2bfloat16(v);
}
__global__ void prep_bt_fin(const float* __restrict__ W, __hip_bfloat16* __restrict__ Bt)
{
    int c = blockIdx.x, k = threadIdx.x;
    if (k >= KP) return;
    float v = (c < 200 && k < 200) ? W[(size_t)k * 200 + c] : 0.f;
    Bt[(size_t)c * KP + k] = __float2bfloat16(v);
}

// -------- layer-1 fused (both heads): 25 tiles = xa1_h0|xa1_h1|xa2_h0|xa2_h1
__global__ __launch_bounds__(256)
void l1_both_k(const float* __restrict__ ent, const float* __restrict__ nscale,
               const __hip_bfloat16* __restrict__ Bt,  // [400][KP]
               const float* __restrict__ a2h,          // [2][100]
               __hip_bfloat16* __restrict__ x1,        // [N][KP] (cols 0-199)
               __hip_bfloat16* __restrict__ pB,        // [N][PBS] interleaved + s2 pad
               float* __restrict__ s1,                 // [2][N]
               int M)
{
    __shared__ __align__(16) __hip_bfloat16 Bs[400 * LDSW];  // 32 KB
    int tid = threadIdx.x, wave = tid >> 6, lane = tid & 63;
    int quad = lane >> 4, l16 = lane & 15;
    int m0 = blockIdx.x * 64;
    int arow = m0 + wave * 16 + l16;
    bool rok = arow < M;
    float nsc = rok ? nscale[arow] : 0.f;
    const float* arp = ent + (size_t)arow * DD;

    f32x4 acc[25];
#pragma unroll
    for (int t = 0; t < 25; t++) acc[t] = (f32x4){0.f, 0.f, 0.f, 0.f};

    short8 stg[7];
#pragma unroll
    for (int i = 0; i < 7; i++) {
        int idx = tid + i * 256;
        if (idx < 1600) {
            int r = idx >> 2, c8 = idx & 3;
            stg[i] = *(const short8*)(Bt + (size_t)r * KP + c8 * 8);
        }
    }

    for (int ch = 0; ch < 7; ch++) {
#pragma unroll
        for (int i = 0; i < 7; i++) {
            int idx = tid + i * 256;
            if (idx < 1600) {
                int r = idx >> 2, c8 = idx & 3;
                *(short8*)(Bs + r * LDSW + c8 * 8) = stg[i];
            }
        }
        __syncthreads();
        if (ch < 6) {
            int kb2 = (ch + 1) * 32;
#pragma unroll
            for (int i = 0; i < 7; i++) {
                int idx = tid + i * 256;
                if (idx < 1600) {
                    int r = idx >> 2, c8 = idx & 3;
                    stg[i] = *(const short8*)(Bt + (size_t)r * KP + kb2 + c8 * 8);
                }
            }
        }
        int kb = ch * 32 + quad * 8;
        float av[8];
        if (rok && kb + 8 <= DD) {
            const float4* p = (const float4*)(arp + kb);
            float4 u0 = p[0], u1 = p[1];
            av[0] = u0.x; av[1] = u0.y; av[2] = u0.z; av[3] = u0.w;
            av[4] = u1.x; av[5] = u1.y; av[6] = u1.z; av[7] = u1.w;
        } else {
#pragma unroll
            for (int j = 0; j < 8; j++) av[j] = (rok && kb + j < DD) ? arp[kb + j] : 0.f;
        }
        short8 a;
#pragma unroll
        for (int j = 0; j < 8; j++) a[j] = bf16s(av[j] * nsc);
        const __hip_bfloat16* bp = Bs + (size_t)l16 * LDSW + quad * 8;
#pragma unroll
        for (int t = 0; t < 25; t++) {
            short8 b = *(const short8*)(bp + (size_t)t * 16 * LDSW);
            acc[t] = __builtin_amdgcn_mfma_f32_16x16x32_bf16(a, b, acc[t], 0, 0, 0);
        }
        __syncthreads();
    }

    int orow = m0 + wave * 16 + quad * 4;
    float d0[4] = {0,0,0,0}, d1[4] = {0,0,0,0}, d2[4] = {0,0,0,0}, d3[4] = {0,0,0,0};
#pragma unroll
    for (int t = 0; t < 25; t++) {
        int c = t * 16 + l16;
        int seg = c / 100, idx = c - seg * 100;
        float w = a2h[(seg & 1) * 100 + idx];
#pragma unroll
        for (int i = 0; i < 4; i++) {
            float v = acc[t][i];
            float vw = v * w;
            if (seg == 0) d0[i] += vw;
            else if (seg == 1) d1[i] += vw;
            else if (seg == 2) d2[i] += vw;
            else d3[i] += vw;
            int gm = orow + i;
            if (gm < M) {
                if (seg < 2) x1[(size_t)gm * KP + c] = __float2bfloat16(v);
                else pB[(size_t)gm * PBS + idx * 2 + (seg - 2)] = __float2bfloat16(v);
            }
        }
    }
#pragma unroll
    for (int msk = 1; msk < 16; msk <<= 1)
#pragma unroll
        for (int i = 0; i < 4; i++) {
            d0[i] += __shfl_xor(d0[i], msk);
            d1[i] += __shfl_xor(d1[i], msk);
            d2[i] += __shfl_xor(d2[i], msk);
            d3[i] += __shfl_xor(d3[i], msk);
        }
    if (l16 == 0)
#pragma unroll
        for (int i = 0; i < 4; i++) {
            int gm = orow + i;
            if (gm < M) {
                s1[gm] = d0[i]; s1[M + gm] = d1[i];
                float2 sv; sv.x = d2[i]; sv.y = d3[i];
                *(float2*)((char*)pB + (size_t)gm * (PBS * 2) + 400) = sv;
            }
        }
}

// -------- layer-2 fused: 25 tiles = x1A1 (f32 -> out_ent) | x1A2 (bf16) ----
__global__ __launch_bounds__(256)
void l2_proj_k(const __hip_bfloat16* __restrict__ x1,  // [N][KP]
               const __hip_bfloat16* __restrict__ Bt,  // [400][KP]
               const float* __restrict__ a2o,          // [200]
               float* __restrict__ x1A1,               // [N][200] (out_ent)
               __hip_bfloat16* __restrict__ x1A2,      // [N][PBS], s2 in pad
               float* __restrict__ s1, int M)
{
    __shared__ __align__(16) __hip_bfloat16 Bs[400 * LDSW];  // 32 KB
    int tid = threadIdx.x, wave = tid >> 6, lane = tid & 63;
    int quad = lane >> 4, l16 = lane & 15;
    int m0 = blockIdx.x * 64;
    int arow = m0 + wave * 16 + l16;
    bool rok = arow < M;
    const __hip_bfloat16* arp = x1 + (size_t)arow * KP;

    f32x4 acc[25];
#pragma unroll
    for (int t = 0; t < 25; t++) acc[t] = (f32x4){0.f, 0.f, 0.f, 0.f};

    short8 stg[7];
#pragma unroll
    for (int i = 0; i < 7; i++) {
        int idx = tid + i * 256;
        if (idx < 1600) {
            int r = idx >> 2, c8 = idx & 3;
            stg[i] = *(const short8*)(Bt + (size_t)r * KP + c8 * 8);
        }
    }

    for (int ch = 0; ch < 7; ch++) {
#pragma unroll
        for (int i = 0; i < 7; i++) {
            int idx = tid + i * 256;
            if (idx < 1600) {
                int r = idx >> 2, c8 = idx & 3;
                *(short8*)(Bs + r * LDSW + c8 * 8) = stg[i];
            }
        }
        __syncthreads();
        if (ch < 6) {
            int kb2 = (ch + 1) * 32;
#pragma unroll
            for (int i = 0; i < 7; i++) {
                int idx = tid + i * 256;
                if (idx < 1600) {
                    int r = idx >> 2, c8 = idx & 3;
                    stg[i] = *(const short8*)(Bt + (size_t)r * KP + kb2 + c8 * 8);
                }
            }
        }
        int kb = ch * 32 + quad * 8;
        short8 a = (short8){0,0,0,0,0,0,0,0};
        if (rok) a = *(const short8*)(arp + kb);
        const __hip_bfloat16* bp = Bs + (size_t)l16 * LDSW + quad * 8;
#pragma unroll
        for (int t = 0; t < 25; t++) {
            short8 b = *(const short8*)(bp + (size_t)t * 16 * LDSW);
            acc[t] = __builtin_amdgcn_mfma_f32_16x16x32_bf16(a, b, acc[t], 0, 0, 0);
        }
        __syncthreads();
    }

    int orow = m0 + wave * 16 + quad * 4;
    float dA[4] = {0,0,0,0}, dB[4] = {0,0,0,0};
#pragma unroll
    for (int t = 0; t < 25; t++) {
        int c = t * 16 + l16;
        bool first = c < 200;
        int cc = first ? c : c - 200;
        float w = a2o[cc];
#pragma unroll
        for (int i = 0; i < 4; i++) {
            float v = acc[t][i];
            int gm = orow + i;
            if (first) {
                dA[i] += v * w;
                if (gm < M) x1A1[(size_t)gm * OD + c] = v;
            } else {
                dB[i] += v * w;
                if (gm < M) x1A2[(size_t)gm * PBS + cc] = __float2bfloat16(v);
            }
        }
    }
#pragma unroll
    for (int msk = 1; msk < 16; msk <<= 1)
#pragma unroll
        for (int i = 0; i < 4; i++) {
            dA[i] += __shfl_xor(dA[i], msk);
            dB[i] += __shfl_xor(dB[i], msk);
        }
    if (l16 == 0)
#pragma unroll
        for (int i = 0; i < 4; i++) {
            int gm = orow + i;
            if (gm < M) {
                s1[gm] = dA[i];
                *(float*)((char*)x1A2 + (size_t)gm * (PBS * 2) + 400) = dB[i];
            }
        }
}

// -------- final: out_ent = l2norm(out_ent + (ent*nscale) @ W_ent) ---------
__global__ __launch_bounds__(256)
void final_mfma_k(const float* __restrict__ ent, const float* __restrict__ nscale,
                  const __hip_bfloat16* __restrict__ Bt,  // [208][KP]
                  float* __restrict__ outent, int M)
{
    __shared__ __align__(16) __hip_bfloat16 Bs[208 * LDSW];  // 16.6 KB
    int tid = threadIdx.x, wave = tid >> 6, lane = tid & 63;
    int quad = lane >> 4, l16 = lane & 15;
    int m0 = blockIdx.x * 64;
    int arow = m0 + wave * 16 + l16;
    bool rok = arow < M;
    float nsc = rok ? nscale[arow] : 0.f;
    const float* arp = ent + (size_t)arow * DD;

    f32x4 acc[13];
#pragma unroll
    for (int t = 0; t < 13; t++) acc[t] = (f32x4){0.f, 0.f, 0.f, 0.f};

    short8 stg[4];
#pragma unroll
    for (int i = 0; i < 4; i++) {
        int idx = tid + i * 256;
        if (idx < 832) {
            int r = idx >> 2, c8 = idx & 3;
            stg[i] = *(const short8*)(Bt + (size_t)r * KP + c8 * 8);
        }
    }

    for (int ch = 0; ch < 7; ch++) {
#pragma unroll
        for (int i = 0; i < 4; i++) {
            int idx = tid + i * 256;
            if (idx < 832) {
                int r = idx >> 2, c8 = idx & 3;
                *(short8*)(Bs + r * LDSW + c8 * 8) = stg[i];
            }
        }
        __syncthreads();
        if (ch < 6) {
            int kb2 = (ch + 1) * 32;
#pragma unroll
            for (int i = 0; i < 4; i++) {
                int idx = tid + i * 256;
                if (idx < 832) {
                    int r = idx >> 2, c8 = idx & 3;
                    stg[i] = *(const short8*)(Bt + (size_t)r * KP + kb2 + c8 * 8);
                }
            }
        }
        int kb = ch * 32 + quad * 8;
        float av[8];
        if (rok && kb + 8 <= DD) {
            const float4* p = (const float4*)(arp + kb);
            float4 u0 = p[0], u1 = p[1];
            av[0] = u0.x; av[1] = u0.y; av[2] = u0.z; av[3] = u0.w;
            av[4] = u1.x; av[5] = u1.y; av[6] = u1.z; av[7] = u1.w;
        } else {
#pragma unroll
            for (int j = 0; j < 8; j++) av[j] = (rok && kb + j < DD) ? arp[kb + j] : 0.f;
        }
        short8 a;
#pragma unroll
        for (int j = 0; j < 8; j++) a[j] = bf16s(av[j] * nsc);
        const __hip_bfloat16* bp = Bs + (size_t)l16 * LDSW + quad * 8;
#pragma unroll
        for (int t = 0; t < 13; t++) {
            short8 b = *(const short8*)(bp + (size_t)t * 16 * LDSW);
            acc[t] = __builtin_amdgcn_mfma_f32_16x16x32_bf16(a, b, acc[t], 0, 0, 0);
        }
        __syncthreads();
    }

    int orow = m0 + wave * 16 + quad * 4;
    float ss[4] = {0.f, 0.f, 0.f, 0.f};
#pragma unroll
    for (int t = 0; t < 13; t++) {
        int gn = t * 16 + l16;
#pragma unroll
        for (int i = 0; i < 4; i++) {
            int gm = orow + i;
            float v = 0.f;
            if (gn < OD && gm < M) v = acc[t][i] + outent[(size_t)gm * OD + gn];
            acc[t][i] = v;
            ss[i] += v * v;
        }
    }
#pragma unroll
    for (int msk = 1; msk < 16; msk <<= 1)
#pragma unroll
        for (int i = 0; i < 4; i++) ss[i] += __shfl_xor(ss[i], msk);
    float scl[4];
#pragma unroll
    for (int i = 0; i < 4; i++) scl[i] = 1.f / fmaxf(sqrtf(ss[i]), 1e-12f);
#pragma unroll
    for (int t = 0; t < 13; t++) {
        int gn = t * 16 + l16;
        if (gn >= OD) continue;
#pragma unroll
        for (int i = 0; i < 4; i++) {
            int gm = orow + i;
            if (gm < M) outent[(size_t)gm * OD + gn] = acc[t][i] * scl[i];
        }
    }
}

// -------- generic MFMA GEMM (small R-sized matmuls); cs/co = C col-stride --
#define KPAD 48
template<bool BTr, typename AT, typename CT>
__global__ __launch_bounds__(256)
void gemm_mfma_k(const AT* __restrict__ A, int lda, const float* __restrict__ ascale,
                 const float* __restrict__ B, int ldb, int colOff,
                 CT* __restrict__ C, int ldc, int cs, int co,
                 int M, int Nc, int K)
{
    __shared__ __align__(16) __hip_bfloat16 As[64][KPAD];
    __shared__ __align__(16) __hip_bfloat16 Bs[64][KPAD];
    int tid  = threadIdx.x;
    int wave = tid >> 6, lane = tid & 63;
    int quad = lane >> 4, l16 = lane & 15;
    int n0 = blockIdx.x * 64, m0 = blockIdx.y * 64;
    f32x4 acc[4];
#pragma unroll
    for (int t = 0; t < 4; t++) acc[t] = (f32x4){0.f, 0.f, 0.f, 0.f};

    for (int k0 = 0; k0 < K; k0 += 32) {
        {
            int m = tid >> 2, kc = (tid & 3) * 8;
            int gm = m0 + m;
            float scale = (ascale && gm < M) ? ascale[gm] : 1.f;
#pragma unroll
            for (int j = 0; j < 8; j++) {
                int gk = k0 + kc + j;
                float v = 0.f;
                if (gm < M && gk < K) v = toF(A[(size_t)gm * lda + gk]) * scale;
                As[m][kc + j] = __float2bfloat16(v);
            }
        }
        if (BTr) {
            int n = tid >> 2, kc = (tid & 3) * 8;
            int gn = n0 + n;
#pragma unroll
            for (int j = 0; j < 8; j++) {
                int gk = k0 + kc + j;
                float v = 0.f;
                if (gn < Nc && gk < K) v = B[(size_t)gn * ldb + colOff + gk];
                Bs[n][kc + j] = __float2bfloat16(v);
            }
        } else {
            int n = tid & 63, kq = tid >> 6;
            int gn = n0 + n;
#pragma unroll
            for (int j = 0; j < 8; j++) {
                int gk = k0 + kq * 8 + j;
                float v = 0.f;
                if (gn < Nc && gk < K) v = B[(size_t)gk * ldb + gn];
                Bs[n][kq * 8 + j] = __float2bfloat16(v);
            }
        }
        __syncthreads();
        short8 a = *(const short8*)&As[wave * 16 + l16][quad * 8];
#pragma unroll
        for (int t = 0; t < 4; t++) {
            short8 b = *(const short8*)&Bs[t * 16 + l16][quad * 8];
            acc[t] = __builtin_amdgcn_mfma_f32_16x16x32_bf16(a, b, acc[t], 0, 0, 0);
        }
        __syncthreads();
    }
#pragma unroll
    for (int t = 0; t < 4; t++) {
        int gn = n0 + t * 16 + l16;
        if (gn >= Nc) continue;
#pragma unroll
        for (int i = 0; i < 4; i++) {
            int gm = m0 + wave * 16 + quad * 4 + i;
            if (gm < M) storeC(acc[t][i], &C[(size_t)gm * ldc + (size_t)gn * cs + co]);
        }
    }
}

// -------- row-dot (srel); ks = k-stride in mat, os/oo = output stride ------
template<typename T>
__global__ __launch_bounds__(256)
void rowdot_k(const T* __restrict__ mat, int ld, int coff, int ks,
              const float* __restrict__ vec,
              float* __restrict__ outp, int os, int oo, int M, int Dd)
{
    int wave = (blockIdx.x * blockDim.x + threadIdx.x) >> 6;
    int lane = threadIdx.x & 63;
    if (wave >= M) return;
    float s = 0.f;
    for (int k = lane; k < Dd; k += 64)
        s += toF(mat[(size_t)wave * ld + coff + (size_t)k * ks]) * vec[k];
    for (int o = 32; o > 0; o >>= 1) s += __shfl_down(s, o);
    if (lane == 0) outp[wave * os + oo] = s;
}

// -------- CSR build --------
__device__ inline void decode_edge(const int* __restrict__ el, int E,
                                   const int* __restrict__ etype,
                                   const int* __restrict__ tin, int e,
                                   int& dst, int& src, int& r1, int& r2)
{
    if (e < E) { dst = el[e]; src = el[E + e]; r1 = etype[e]; r2 = -1; }
    else {
        int j = e - E;
        dst = tin[j * 4 + 3]; src = tin[j * 4 + 0];
        r1 = tin[j * 4 + 1];  r2 = tin[j * 4 + 2];
    }
}

__global__ void hist_k(const int* __restrict__ el, int E, const int* __restrict__ etype,
                       const int* __restrict__ tin, int Etot, int* __restrict__ cnt)
{
    int e = blockIdx.x * blockDim.x + threadIdx.x;
    if (e >= Etot) return;
    int dst, src, r1, r2; decode_edge(el, E, etype, tin, e, dst, src, r1, r2);
    atomicAdd(&cnt[dst], 1);
}

__global__ __launch_bounds__(1024)
void scan1_k(const int* __restrict__ cnt, int* __restrict__ start,
             int* __restrict__ aux, int n)
{
    __shared__ int tmp[1024];
    int i = blockIdx.x * 1024 + threadIdx.x;
    int v = (i < n) ? cnt[i] : 0;
    tmp[threadIdx.x] = v;
    __syncthreads();
    for (int o = 1; o < 1024; o <<= 1) {
        int t = (threadIdx.x >= (unsigned)o) ? tmp[threadIdx.x - o] : 0;
        __syncthreads();
        tmp[threadIdx.x] += t;
        __syncthreads();
    }
    if (i < n) start[i] = tmp[threadIdx.x] - v;
    if (threadIdx.x == 1023) aux[blockIdx.x] = tmp[1023];
}

__global__ void scan2_k(int* __restrict__ aux, int nb)
{
    if (threadIdx.x == 0 && blockIdx.x == 0) {
        int s = 0;
        for (int i = 0; i < nb; i++) { int v = aux[i]; aux[i] = s; s += v; }
    }
}

__global__ __launch_bounds__(1024)
void scan3_k(int* __restrict__ start, const int* __restrict__ aux, int n, int Etot)
{
    int i = blockIdx.x * 1024 + threadIdx.x;
    if (i < n) start[i] += aux[blockIdx.x];
    if (i == 0) start[n] = Etot;
}

// csr entry: .x = src, .y = r1 | (r2s<<16), r2s==0xFFFF means "no r2"
__global__ void fill_k(const int* __restrict__ el, int E, const int* __restrict__ etype,
                       const int* __restrict__ tin, int Etot,
                       const int* __restrict__ start, int* __restrict__ fill,
                       int2* __restrict__ csr)
{
    int e = blockIdx.x * blockDim.x + threadIdx.x;
    if (e >= Etot) return;
    int dst, src, r1, r2; decode_edge(el, E, etype, tin, e, dst, src, r1, r2);
    int p = start[dst] + atomicAdd(&fill[dst], 1);
    unsigned r2s = (r2 >= 0) ? (unsigned)r2 : 0xFFFFu;
    csr[p] = make_int2(src, (int)((r2s << 16) | (unsigned)r1));
}

// -------- layer-1 gather: wave/dst, 4-wide predicated blocks, packed loads --
__global__ __launch_bounds__(256)
void gather_l1_k(const int* __restrict__ start, const int2* __restrict__ csr,
                 const float* __restrict__ s1,        // [2][N] dst-side
                 const float* __restrict__ srel2,     // [R][2]
                 const __hip_bfloat16* __restrict__ pB,   // [N][PBS] interleaved
                 const float* __restrict__ rpf2,      // [R][100][2]
                 __hip_bfloat16* __restrict__ x1, int N)  // [N][KP]
{
    int n = (blockIdx.x * blockDim.x + threadIdx.x) >> 6;
    int lane = threadIdx.x & 63;
    if (n >= N) return;
    int b0 = start[n], b1 = start[n + 1];
    float s1h0 = s1[n], s1h1 = s1[N + n];
    float rs0 = 0.f, rs1 = 0.f;
    float2 acc0 = {0.f, 0.f};   // k0: (h0, h1)
    float2 acc1 = {0.f, 0.f};   // k1
    int k0 = lane, k1 = lane + 64;
    bool k1ok = k1 < 100;
    int k1c = k1ok ? k1 : 0;

    for (int base = b0; base < b1; base += 4) {
        float2 vk0[4], vk1[4];
        float w0[4], w1[4];
#pragma unroll
        for (int u = 0; u < 4; u++) {
            int id = base + u;
            bool val = id < b1;
            int2 eg = csr[val ? id : b0];
            unsigned ey = (unsigned)eg.y;
            int r1 = (int)(ey & 0xFFFFu);
            unsigned r2u = ey >> 16;
            bool has2 = (r2u != 0xFFFFu);
            int r2 = has2 ? (int)r2u : 0;
            float f2 = has2 ? 1.f : 0.f;
            const __hip_bfloat16* rA = pB + (unsigned)((unsigned)eg.x * PBS);
            float2 sA = *(const float2*)(rA + 200);
            unsigned pw0 = *(const unsigned*)(rA + 2 * k0);
            unsigned pw1 = *(const unsigned*)(rA + 2 * k1c);
            const float2* q1 = (const float2*)(rpf2 + (unsigned)r1 * 200);
            const float2* q2 = (const float2*)(rpf2 + (unsigned)r2 * 200);
            float2 sr1v = *(const float2*)(srel2 + r1 * 2);
            float2 sr2v = *(const float2*)(srel2 + r2 * 2);
            float2 q1a = q1[k0], q1b = q1[k1c];
            float2 q2a = q2[k0], q2b = q2[k1c];
            vk0[u].x = bfLo(pw0) + q1a.x + f2 * q2a.x;
            vk0[u].y = bfHi(pw0) + q1a.y + f2 * q2a.y;
            vk1[u].x = bfLo(pw1) + q1b.x + f2 * q2b.x;
            vk1[u].y = bfHi(pw1) + q1b.y + f2 * q2b.y;
            float z0 = s1h0 + sA.x + sr1v.x + f2 * sr2v.x;
            float z1 = s1h1 + sA.y + sr1v.y + f2 * sr2v.y;
            float e0 = expf(-(z0 > 0.f ? z0 : 0.2f * z0));
            float e1 = expf(-(z1 > 0.f ? z1 : 0.2f * z1));
            w0[u] = val ? e0 : 0.f;
            w1[u] = val ? e1 : 0.f;
        }
#pragma unroll
        for (int u = 0; u < 4; u++) {
            rs0 += w0[u]; rs1 += w1[u];
            acc0.x += w0[u] * vk0[u].x; acc0.y += w1[u] * vk0[u].y;
            acc1.x += w0[u] * vk1[u].x; acc1.y += w1[u] * vk1[u].y;
        }
    }

    float i0 = rs0 > 0.f ? 1.f / rs0 : 0.f;
    float i1 = rs1 > 0.f ? 1.f / rs1 : 0.f;
    __hip_bfloat16* xr = x1 + (size_t)n * KP;
    float hp;
    hp = rs0 > 0.f ? toF(xr[k0]) + acc0.x * i0 : 0.f;
    xr[k0] = __float2bfloat16(hp > 0.f ? hp : expf(hp) - 1.f);
    hp = rs1 > 0.f ? toF(xr[100 + k0]) + acc0.y * i1 : 0.f;
    xr[100 + k0] = __float2bfloat16(hp > 0.f ? hp : expf(hp) - 1.f);
    if (k1ok) {
        hp = rs0 > 0.f ? toF(xr[k1]) + acc1.x * i0 : 0.f;
        xr[k1] = __float2bfloat16(hp > 0.f ? hp : expf(hp) - 1.f);
        hp = rs1 > 0.f ? toF(xr[100 + k1]) + acc1.y * i1 : 0.f;
        xr[100 + k1] = __float2bfloat16(hp > 0.f ? hp : expf(hp) - 1.f);
    }
}

// -------- layer-2 gather: wave/dst, 4-wide predicated blocks, packed loads --
__global__ __launch_bounds__(256)
void gather_l2_k(const int* __restrict__ start, const int2* __restrict__ csr,
                 const float* __restrict__ s1,
                 const float* __restrict__ srel,          // [R]
                 const __hip_bfloat16* __restrict__ x1A2, // [N][PBS] + s2 in pad
                 const float* __restrict__ rpf,           // [R][200]
                 const float* __restrict__ maskf,
                 float* __restrict__ outent, int N)       // [N][200], holds x1A1
{
    int n = (blockIdx.x * blockDim.x + threadIdx.x) >> 6;
    int lane = threadIdx.x & 63;
    if (n >= N) return;
    int b0 = start[n], b1 = start[n + 1];
    float s1n = s1[n];
    float rs = 0.f;
    float2 a0 = {0.f, 0.f};   // k = 2*lane, 2*lane+1
    float2 a1 = {0.f, 0.f};   // k = 128+2*lane, +1 (lane<36)
    int j0 = 2 * lane;
    bool j1ok = lane < 36;
    int j1 = j1ok ? (128 + 2 * lane) : 0;

    for (int base = b0; base < b1; base += 4) {
        float2 v0[4], v1[4];
        float w[4];
#pragma unroll
        for (int u = 0; u < 4; u++) {
            int id = base + u;
            bool val = id < b1;
            int2 eg = csr[val ? id : b0];
            unsigned ey = (unsigned)eg.y;
            int r1 = (int)(ey & 0xFFFFu);
            unsigned r2u = ey >> 16;
            bool has2 = (r2u != 0xFFFFu);
            int r2 = has2 ? (int)r2u : 0;
            float f2 = has2 ? 1.f : 0.f;
            const __hip_bfloat16* xs = x1A2 + (unsigned)((unsigned)eg.x * PBS);
            float s2v = *(const float*)(xs + 200);
            unsigned xw0 = *(const unsigned*)(xs + j0);
            unsigned xw1 = *(const unsigned*)(xs + j1);
            const float* q1 = rpf + (unsigned)r1 * 200;
            const float* q2 = rpf + (unsigned)r2 * 200;
            float2 q1a = *(const float2*)(q1 + j0);
            float2 q1b = *(const float2*)(q1 + j1);
            float2 q2a = *(const float2*)(q2 + j0);
            float2 q2b = *(const float2*)(q2 + j1);
            float sr = srel[r1] + f2 * srel[r2];
            v0[u].x = bfLo(xw0) + q1a.x + f2 * q2a.x;
            v0[u].y = bfHi(xw0) + q1a.y + f2 * q2a.y;
            v1[u].x = bfLo(xw1) + q1b.x + f2 * q2b.x;
            v1[u].y = bfHi(xw1) + q1b.y + f2 * q2b.y;
            float z = s1n + s2v + sr;
            float e = expf(-(z > 0.f ? z : 0.2f * z));
            w[u] = val ? e : 0.f;
        }
#pragma unroll
        for (int u = 0; u < 4; u++) {
            rs += w[u];
            a0.x += w[u] * v0[u].x; a0.y += w[u] * v0[u].y;
            a1.x += w[u] * v1[u].x; a1.y += w[u] * v1[u].y;
        }
    }

    float inv = rs > 0.f ? 1.f / rs : 0.f;
    float mk = maskf[n];
    float* orow = outent + (size_t)n * 200;
    {
        float2 o = *(const float2*)(orow + j0);
        float hpx = rs > 0.f ? o.x + a0.x * inv : 0.f;
        float hpy = rs > 0.f ? o.y + a0.y * inv : 0.f;
        float2 r;
        r.x = mk * (hpx > 0.f ? hpx : expf(hpx) - 1.f);
        r.y = mk * (hpy > 0.f ? hpy : expf(hpy) - 1.f);
        *(float2*)(orow + j0) = r;
    }
    if (j1ok) {
        float2 o = *(const float2*)(orow + j1);
        float hpx = rs > 0.f ? o.x + a1.x * inv : 0.f;
        float hpy = rs > 0.f ? o.y + a1.y * inv : 0.f;
        float2 r;
        r.x = mk * (hpx > 0.f ? hpx : expf(hpx) - 1.f);
        r.y = mk * (hpy > 0.f ? hpy : expf(hpy) - 1.f);
        *(float2*)(orow + j1) = r;
    }
}

__global__ void scatter_mask_k(const int* __restrict__ batch, int NB,
                               float* __restrict__ masko)
{
    int i = blockIdx.x * blockDim.x + threadIdx.x;
    if (i >= NB) return;
    masko[batch[i]] = 1.0f;
}

extern "C" void kernel_launch(void* const* d_in, const int* in_sizes, int n_in,
                              void* d_out, int out_size, void* d_ws, size_t ws_size,
                              hipStream_t stream)
{
    const float* ent      = (const float*)d_in[0];
    const float* rel      = (const float*)d_in[1];
    const float* W_ent    = (const float*)d_in[2];
    const float* W_gat    = (const float*)d_in[3];
    const float* a_heads  = (const float*)d_in[4];
    const float* a2_heads = (const float*)d_in[5];
    const float* a_out    = (const float*)d_in[6];
    const float* a2_out   = (const float*)d_in[7];
    const int* batch = (const int*)d_in[8];
    const int* el    = (const int*)d_in[9];
    const int* etype = (const int*)d_in[10];
    const int* tin   = (const int*)d_in[11];

    const int N   = in_sizes[0] / DD;   // 50000
    const int R   = in_sizes[1] / DD;   // 500
    const int NB  = in_sizes[8];        // 20000
    const int E   = in_sizes[9] / 2;    // 150000
    const int ENH = in_sizes[11] / 4;   // 30000
    const int Etot = E + ENH;

    // ---- workspace ----
    char* ws = (char*)d_ws;
    size_t off = 0;
    auto take = [&](size_t bytes) { size_t o = off; off += (bytes + 255) & ~(size_t)255; return o; };
    size_t o_R1   = take((size_t)N * KP * 2);     // x1 bf16 [N][KP]
    size_t o_R2   = take((size_t)N * PBS * 2);    // pB [N][PBS]; later x1A2 [N][PBS]
    size_t o_rpf  = take((size_t)2 * R * 100 * 4);// rpf2 [R][100][2] / layer2 rpf [R][200]
    size_t o_bt1  = take((size_t)400 * KP * 2);
    size_t o_bt2  = take((size_t)400 * KP * 2);
    size_t o_btf  = take((size_t)208 * KP * 2);
    size_t o_nsc  = take((size_t)N * 4);
    size_t o_s1   = take((size_t)2 * N * 4);      // aliased by cnt during CSR build
    size_t o_srel = take((size_t)2 * R * 4);      // [R][2] layer1 / [R] layer2
    size_t o_csr  = take((size_t)Etot * 8);
    size_t o_str  = take((size_t)(N + 1) * 4);
    size_t o_aux  = take((size_t)64 * 4);

    __hip_bfloat16* x1   = (__hip_bfloat16*)(ws + o_R1);
    __hip_bfloat16* pB   = (__hip_bfloat16*)(ws + o_R2);
    __hip_bfloat16* x1A2 = (__hip_bfloat16*)(ws + o_R2);
    float* rpf2   = (float*)(ws + o_rpf);
    __hip_bfloat16* bt1 = (__hip_bfloat16*)(ws + o_bt1);
    __hip_bfloat16* bt2 = (__hip_bfloat16*)(ws + o_bt2);
    __hip_bfloat16* btf = (__hip_bfloat16*)(ws + o_btf);
    float* nscale = (float*)(ws + o_nsc);
    float* s1     = (float*)(ws + o_s1);
    float* srel2  = (float*)(ws + o_srel);
    int2*  csr    = (int2*)(ws + o_csr);
    int*   cnt    = (int*)(ws + o_s1);   // CSR-build scratch; dead before l1_both_k writes s1
    int*   startA = (int*)(ws + o_str);
    int*   aux    = (int*)(ws + o_aux);

    float* out       = (float*)d_out;
    float* out_ent   = out;                                     // [N,200]
    float* out_rel_o = out + (size_t)N * OD;                    // [500,200]
    float* out_mask  = out + (size_t)N * OD + (size_t)R * OD;   // [N]

    const int nblk = cdiv(N, 64);
    const int nbScan = cdiv(N, 1024);

    // A. prep: norms, B panels, x1 pad; out_rel GEMM
    rownorm_inv_k<<<cdiv(N, 4), 256, 0, stream>>>(ent, nscale, N, DD);
    prep_bt_l1<<<400, 256, 0, stream>>>(a_heads, bt1);
    prep_bt_l2<<<400, 256, 0, stream>>>(a_out, bt2);
    prep_bt_fin<<<208, 256, 0, stream>>>(W_ent, btf);
    hipMemsetAsync(x1, 0, (size_t)N * KP * 2, stream);
    gemm_mfma_k<false, float, float><<<dim3(cdiv(OD, 64), cdiv(R, 64)), 256, 0, stream>>>(
        rel, DD, nullptr, W_gat, OD, 0, out_rel_o, OD, 1, 0, R, OD, DD);

    // A2. CSR build (dst-grouped edge lists)
    hipMemsetAsync(cnt, 0, (size_t)N * 4, stream);
    hist_k<<<cdiv(Etot, 256), 256, 0, stream>>>(el, E, etype, tin, Etot, cnt);
    scan1_k<<<nbScan, 1024, 0, stream>>>(cnt, startA, aux, N);
    scan2_k<<<1, 64, 0, stream>>>(aux, nbScan);
    scan3_k<<<nbScan, 1024, 0, stream>>>(startA, aux, N, Etot);
    hipMemsetAsync(cnt, 0, (size_t)N * 4, stream);
    fill_k<<<cdiv(Etot, 256), 256, 0, stream>>>(el, E, etype, tin, Etot, startA, cnt, csr);

    // B. layer-1 projections (both heads) + rel projections + gather
    l1_both_k<<<nblk, 256, 0, stream>>>(ent, nscale, bt1, a2_heads, x1, pB, s1, N);
    for (int h = 0; h < 2; h++) {
        const float* ah  = a_heads + (size_t)h * NHID * 600;
        const float* a2h = a2_heads + (size_t)h * NHID;
        gemm_mfma_k<true, float, float><<<dim3(cdiv(NHID, 64), cdiv(R, 64)), 256, 0, stream>>>(
            rel, DD, nullptr, ah, 600, 400, rpf2, 200, 2, h, R, NHID, DD);
        rowdot_k<float><<<cdiv(R, 4), 256, 0, stream>>>(
            rpf2, 200, h, 2, a2h, srel2, 2, h, R, NHID);
    }
    gather_l1_k<<<cdiv(N, 4), 256, 0, stream>>>(
        startA, csr, s1, srel2, pB, rpf2, x1, N);
    // pB dead; R2 becomes x1A2.

    // C. layer-2 projection + rel side
    l2_proj_k<<<nblk, 256, 0, stream>>>(x1, bt2, a2_out, out_ent, x1A2, s1, N);
    gemm_mfma_k<true, float, float><<<dim3(cdiv(OD, 64), cdiv(R, 64)), 256, 0, stream>>>(
        out_rel_o, OD, nullptr, a_out, 600, 400, rpf2, OD, 1, 0, R, OD, OD);
    rowdot_k<float><<<cdiv(R, 4), 256, 0, stream>>>(rpf2, OD, 0, 1, a2_out, srel2, 1, 0, R, OD);

    // D. mask; layer-2 gather (fused combine, single 200-wide pass)
    hipMemsetAsync(out_mask, 0, (size_t)N * 4, stream);
    scatter_mask_k<<<cdiv(NB, 256), 256, 0, stream>>>(batch, NB, out_mask);
    gather_l2_k<<<cdiv(N, 4), 256, 0, stream>>>(
        startA, csr, s1, srel2, x1A2, rpf2, out_mask, out_ent, N);

    // E. fused final GEMM + l2norm
    final_mfma_k<<<nblk, 256, 0, stream>>>(ent, nscale, btf, out_ent, N);
}

// Round 4
// 535.869 us; speedup vs baseline: 1.0611x; 1.0611x over previous
//
#include <hip/hip_runtime.h>
#include <hip/hip_bf16.h>
#include <math.h>

// SpKBGAT: N=50000, D=200, R=500, NHID=100, H=2, OD=200, E=150000, ENH=30000.
// R12: R11's 4-wide gather failed (VGPR stayed 32 -> compiler serialized the
// 4 edges; dummy/always-r2 loads added 50% work). Fix: phase-split gather --
// phase A = pure loads into per-edge arrays (wave-uniform branches skip tail
// and absent-r2 loads), phase B = all compute. Live load results across the
// A/B boundary force concurrent chains. launch_bounds(256,2) lifts VGPR cap.
#define DD   200
#define NHID 100
#define OD   200
#define KP   224   // padded K (7 chunks of 32)
#define PBS  224   // padded row stride (bf16) for pB / x1A2: 448 B
                   // pB: [k][h0,h1] pairs k<100; bytes 400..407 = s2 floats
                   // x1A2: 200 contiguous feats; byte 400 = s2 float
#define LDSW 40    // LDS row stride in shorts (80 B)

typedef __attribute__((ext_vector_type(8))) short short8;
typedef __attribute__((ext_vector_type(4))) float f32x4;

static inline int cdiv(int a, int b) { return (a + b - 1) / b; }

__device__ inline float toF(float x) { return x; }
__device__ inline float toF(__hip_bfloat16 x) { return __bfloat162float(x); }
__device__ inline void storeC(float v, float* p) { *p = v; }
__device__ inline void storeC(float v, __hip_bfloat16* p) { *p = __float2bfloat16(v); }
__device__ inline short bf16s(float f) {
    __hip_bfloat16 h = __float2bfloat16(f);
    short s; __builtin_memcpy(&s, &h, 2); return s;
}
__device__ inline float bfLo(unsigned u) { return __uint_as_float(u << 16); }
__device__ inline float bfHi(unsigned u) { return __uint_as_float(u & 0xFFFF0000u); }

// -------- per-row inverse L2 norm (f32), wave per row --------
__global__ __launch_bounds__(256)
void rownorm_inv_k(const float* __restrict__ in, float* __restrict__ sc, int M, int Dd)
{
    int wave = (blockIdx.x * blockDim.x + threadIdx.x) >> 6;
    int lane = threadIdx.x & 63;
    if (wave >= M) return;
    float ss = 0.f;
    for (int k = lane; k < Dd; k += 64) {
        float x = in[(size_t)wave * Dd + k];
        ss += x * x;
    }
    for (int o = 32; o > 0; o >>= 1) ss += __shfl_down(ss, o);
    if (lane == 0) sc[wave] = 1.f / fmaxf(sqrtf(ss), 1e-12f);
}

// -------- B-panel prep: bf16 [col][KP], zero-padded --------
__global__ void prep_bt_l1(const float* __restrict__ ah, __hip_bfloat16* __restrict__ Bt)
{
    int c = blockIdx.x, k = threadIdx.x;
    if (k >= KP) return;
    int seg = c / 100, idx = c - seg * 100;
    int h = seg & 1, off = (seg >> 1) * 200;
    float v = (k < 200) ? ah[(size_t)(h * 100 + idx) * 600 + off + k] : 0.f;
    Bt[(size_t)c * KP + k] = __float2bfloat16(v);
}
__global__ void prep_bt_l2(const float* __restrict__ ao, __hip_bfloat16* __restrict__ Bt)
{
    int c = blockIdx.x, k = threadIdx.x;
    if (k >= KP) return;
    int row = (c < 200) ? c : c - 200;
    int off = (c < 200) ? 0 : 200;
    float v = (k < 200) ? ao[(size_t)row * 600 + off + k] : 0.f;
    Bt[(size_t)c * KP + k] = __float2bfloat16(v);
}
__global__ void prep_bt_fin(const float* __restrict__ W, __hip_bfloat16* __restrict__ Bt)
{
    int c = blockIdx.x, k = threadIdx.x;
    if (k >= KP) return;
    float v = (c < 200 && k < 200) ? W[(size_t)k * 200 + c] : 0.f;
    Bt[(size_t)c * KP + k] = __float2bfloat16(v);
}

// -------- layer-1 fused (both heads): 25 tiles = xa1_h0|xa1_h1|xa2_h0|xa2_h1
__global__ __launch_bounds__(256)
void l1_both_k(const float* __restrict__ ent, const float* __restrict__ nscale,
               const __hip_bfloat16* __restrict__ Bt,  // [400][KP]
               const float* __restrict__ a2h,          // [2][100]
               __hip_bfloat16* __restrict__ x1,        // [N][KP] (cols 0-199)
               __hip_bfloat16* __restrict__ pB,        // [N][PBS] interleaved + s2 pad
               float* __restrict__ s1,                 // [2][N]
               int M)
{
    __shared__ __align__(16) __hip_bfloat16 Bs[400 * LDSW];  // 32 KB
    int tid = threadIdx.x, wave = tid >> 6, lane = tid & 63;
    int quad = lane >> 4, l16 = lane & 15;
    int m0 = blockIdx.x * 64;
    int arow = m0 + wave * 16 + l16;
    bool rok = arow < M;
    float nsc = rok ? nscale[arow] : 0.f;
    const float* arp = ent + (size_t)arow * DD;

    f32x4 acc[25];
#pragma unroll
    for (int t = 0; t < 25; t++) acc[t] = (f32x4){0.f, 0.f, 0.f, 0.f};

    short8 stg[7];
#pragma unroll
    for (int i = 0; i < 7; i++) {
        int idx = tid + i * 256;
        if (idx < 1600) {
            int r = idx >> 2, c8 = idx & 3;
            stg[i] = *(const short8*)(Bt + (size_t)r * KP + c8 * 8);
        }
    }

    for (int ch = 0; ch < 7; ch++) {
#pragma unroll
        for (int i = 0; i < 7; i++) {
            int idx = tid + i * 256;
            if (idx < 1600) {
                int r = idx >> 2, c8 = idx & 3;
                *(short8*)(Bs + r * LDSW + c8 * 8) = stg[i];
            }
        }
        __syncthreads();
        if (ch < 6) {
            int kb2 = (ch + 1) * 32;
#pragma unroll
            for (int i = 0; i < 7; i++) {
                int idx = tid + i * 256;
                if (idx < 1600) {
                    int r = idx >> 2, c8 = idx & 3;
                    stg[i] = *(const short8*)(Bt + (size_t)r * KP + kb2 + c8 * 8);
                }
            }
        }
        int kb = ch * 32 + quad * 8;
        float av[8];
        if (rok && kb + 8 <= DD) {
            const float4* p = (const float4*)(arp + kb);
            float4 u0 = p[0], u1 = p[1];
            av[0] = u0.x; av[1] = u0.y; av[2] = u0.z; av[3] = u0.w;
            av[4] = u1.x; av[5] = u1.y; av[6] = u1.z; av[7] = u1.w;
        } else {
#pragma unroll
            for (int j = 0; j < 8; j++) av[j] = (rok && kb + j < DD) ? arp[kb + j] : 0.f;
        }
        short8 a;
#pragma unroll
        for (int j = 0; j < 8; j++) a[j] = bf16s(av[j] * nsc);
        const __hip_bfloat16* bp = Bs + (size_t)l16 * LDSW + quad * 8;
#pragma unroll
        for (int t = 0; t < 25; t++) {
            short8 b = *(const short8*)(bp + (size_t)t * 16 * LDSW);
            acc[t] = __builtin_amdgcn_mfma_f32_16x16x32_bf16(a, b, acc[t], 0, 0, 0);
        }
        __syncthreads();
    }

    int orow = m0 + wave * 16 + quad * 4;
    float d0[4] = {0,0,0,0}, d1[4] = {0,0,0,0}, d2[4] = {0,0,0,0}, d3[4] = {0,0,0,0};
#pragma unroll
    for (int t = 0; t < 25; t++) {
        int c = t * 16 + l16;
        int seg = c / 100, idx = c - seg * 100;
        float w = a2h[(seg & 1) * 100 + idx];
#pragma unroll
        for (int i = 0; i < 4; i++) {
            float v = acc[t][i];
            float vw = v * w;
            if (seg == 0) d0[i] += vw;
            else if (seg == 1) d1[i] += vw;
            else if (seg == 2) d2[i] += vw;
            else d3[i] += vw;
            int gm = orow + i;
            if (gm < M) {
                if (seg < 2) x1[(size_t)gm * KP + c] = __float2bfloat16(v);
                else pB[(size_t)gm * PBS + idx * 2 + (seg - 2)] = __float2bfloat16(v);
            }
        }
    }
#pragma unroll
    for (int msk = 1; msk < 16; msk <<= 1)
#pragma unroll
        for (int i = 0; i < 4; i++) {
            d0[i] += __shfl_xor(d0[i], msk);
            d1[i] += __shfl_xor(d1[i], msk);
            d2[i] += __shfl_xor(d2[i], msk);
            d3[i] += __shfl_xor(d3[i], msk);
        }
    if (l16 == 0)
#pragma unroll
        for (int i = 0; i < 4; i++) {
            int gm = orow + i;
            if (gm < M) {
                s1[gm] = d0[i]; s1[M + gm] = d1[i];
                float2 sv; sv.x = d2[i]; sv.y = d3[i];
                *(float2*)((char*)pB + (size_t)gm * (PBS * 2) + 400) = sv;
            }
        }
}

// -------- layer-2 fused: 25 tiles = x1A1 (f32 -> out_ent) | x1A2 (bf16) ----
__global__ __launch_bounds__(256)
void l2_proj_k(const __hip_bfloat16* __restrict__ x1,  // [N][KP]
               const __hip_bfloat16* __restrict__ Bt,  // [400][KP]
               const float* __restrict__ a2o,          // [200]
               float* __restrict__ x1A1,               // [N][200] (out_ent)
               __hip_bfloat16* __restrict__ x1A2,      // [N][PBS], s2 in pad
               float* __restrict__ s1, int M)
{
    __shared__ __align__(16) __hip_bfloat16 Bs[400 * LDSW];  // 32 KB
    int tid = threadIdx.x, wave = tid >> 6, lane = tid & 63;
    int quad = lane >> 4, l16 = lane & 15;
    int m0 = blockIdx.x * 64;
    int arow = m0 + wave * 16 + l16;
    bool rok = arow < M;
    const __hip_bfloat16* arp = x1 + (size_t)arow * KP;

    f32x4 acc[25];
#pragma unroll
    for (int t = 0; t < 25; t++) acc[t] = (f32x4){0.f, 0.f, 0.f, 0.f};

    short8 stg[7];
#pragma unroll
    for (int i = 0; i < 7; i++) {
        int idx = tid + i * 256;
        if (idx < 1600) {
            int r = idx >> 2, c8 = idx & 3;
            stg[i] = *(const short8*)(Bt + (size_t)r * KP + c8 * 8);
        }
    }

    for (int ch = 0; ch < 7; ch++) {
#pragma unroll
        for (int i = 0; i < 7; i++) {
            int idx = tid + i * 256;
            if (idx < 1600) {
                int r = idx >> 2, c8 = idx & 3;
                *(short8*)(Bs + r * LDSW + c8 * 8) = stg[i];
            }
        }
        __syncthreads();
        if (ch < 6) {
            int kb2 = (ch + 1) * 32;
#pragma unroll
            for (int i = 0; i < 7; i++) {
                int idx = tid + i * 256;
                if (idx < 1600) {
                    int r = idx >> 2, c8 = idx & 3;
                    stg[i] = *(const short8*)(Bt + (size_t)r * KP + kb2 + c8 * 8);
                }
            }
        }
        int kb = ch * 32 + quad * 8;
        short8 a = (short8){0,0,0,0,0,0,0,0};
        if (rok) a = *(const short8*)(arp + kb);
        const __hip_bfloat16* bp = Bs + (size_t)l16 * LDSW + quad * 8;
#pragma unroll
        for (int t = 0; t < 25; t++) {
            short8 b = *(const short8*)(bp + (size_t)t * 16 * LDSW);
            acc[t] = __builtin_amdgcn_mfma_f32_16x16x32_bf16(a, b, acc[t], 0, 0, 0);
        }
        __syncthreads();
    }

    int orow = m0 + wave * 16 + quad * 4;
    float dA[4] = {0,0,0,0}, dB[4] = {0,0,0,0};
#pragma unroll
    for (int t = 0; t < 25; t++) {
        int c = t * 16 + l16;
        bool first = c < 200;
        int cc = first ? c : c - 200;
        float w = a2o[cc];
#pragma unroll
        for (int i = 0; i < 4; i++) {
            float v = acc[t][i];
            int gm = orow + i;
            if (first) {
                dA[i] += v * w;
                if (gm < M) x1A1[(size_t)gm * OD + c] = v;
            } else {
                dB[i] += v * w;
                if (gm < M) x1A2[(size_t)gm * PBS + cc] = __float2bfloat16(v);
            }
        }
    }
#pragma unroll
    for (int msk = 1; msk < 16; msk <<= 1)
#pragma unroll
        for (int i = 0; i < 4; i++) {
            dA[i] += __shfl_xor(dA[i], msk);
            dB[i] += __shfl_xor(dB[i], msk);
        }
    if (l16 == 0)
#pragma unroll
        for (int i = 0; i < 4; i++) {
            int gm = orow + i;
            if (gm < M) {
                s1[gm] = dA[i];
                *(float*)((char*)x1A2 + (size_t)gm * (PBS * 2) + 400) = dB[i];
            }
        }
}

// -------- final: out_ent = l2norm(out_ent + (ent*nscale) @ W_ent) ---------
__global__ __launch_bounds__(256)
void final_mfma_k(const float* __restrict__ ent, const float* __restrict__ nscale,
                  const __hip_bfloat16* __restrict__ Bt,  // [208][KP]
                  float* __restrict__ outent, int M)
{
    __shared__ __align__(16) __hip_bfloat16 Bs[208 * LDSW];  // 16.6 KB
    int tid = threadIdx.x, wave = tid >> 6, lane = tid & 63;
    int quad = lane >> 4, l16 = lane & 15;
    int m0 = blockIdx.x * 64;
    int arow = m0 + wave * 16 + l16;
    bool rok = arow < M;
    float nsc = rok ? nscale[arow] : 0.f;
    const float* arp = ent + (size_t)arow * DD;

    f32x4 acc[13];
#pragma unroll
    for (int t = 0; t < 13; t++) acc[t] = (f32x4){0.f, 0.f, 0.f, 0.f};

    short8 stg[4];
#pragma unroll
    for (int i = 0; i < 4; i++) {
        int idx = tid + i * 256;
        if (idx < 832) {
            int r = idx >> 2, c8 = idx & 3;
            stg[i] = *(const short8*)(Bt + (size_t)r * KP + c8 * 8);
        }
    }

    for (int ch = 0; ch < 7; ch++) {
#pragma unroll
        for (int i = 0; i < 4; i++) {
            int idx = tid + i * 256;
            if (idx < 832) {
                int r = idx >> 2, c8 = idx & 3;
                *(short8*)(Bs + r * LDSW + c8 * 8) = stg[i];
            }
        }
        __syncthreads();
        if (ch < 6) {
            int kb2 = (ch + 1) * 32;
#pragma unroll
            for (int i = 0; i < 4; i++) {
                int idx = tid + i * 256;
                if (idx < 832) {
                    int r = idx >> 2, c8 = idx & 3;
                    stg[i] = *(const short8*)(Bt + (size_t)r * KP + kb2 + c8 * 8);
                }
            }
        }
        int kb = ch * 32 + quad * 8;
        float av[8];
        if (rok && kb + 8 <= DD) {
            const float4* p = (const float4*)(arp + kb);
            float4 u0 = p[0], u1 = p[1];
            av[0] = u0.x; av[1] = u0.y; av[2] = u0.z; av[3] = u0.w;
            av[4] = u1.x; av[5] = u1.y; av[6] = u1.z; av[7] = u1.w;
        } else {
#pragma unroll
            for (int j = 0; j < 8; j++) av[j] = (rok && kb + j < DD) ? arp[kb + j] : 0.f;
        }
        short8 a;
#pragma unroll
        for (int j = 0; j < 8; j++) a[j] = bf16s(av[j] * nsc);
        const __hip_bfloat16* bp = Bs + (size_t)l16 * LDSW + quad * 8;
#pragma unroll
        for (int t = 0; t < 13; t++) {
            short8 b = *(const short8*)(bp + (size_t)t * 16 * LDSW);
            acc[t] = __builtin_amdgcn_mfma_f32_16x16x32_bf16(a, b, acc[t], 0, 0, 0);
        }
        __syncthreads();
    }

    int orow = m0 + wave * 16 + quad * 4;
    float ss[4] = {0.f, 0.f, 0.f, 0.f};
#pragma unroll
    for (int t = 0; t < 13; t++) {
        int gn = t * 16 + l16;
#pragma unroll
        for (int i = 0; i < 4; i++) {
            int gm = orow + i;
            float v = 0.f;
            if (gn < OD && gm < M) v = acc[t][i] + outent[(size_t)gm * OD + gn];
            acc[t][i] = v;
            ss[i] += v * v;
        }
    }
#pragma unroll
    for (int msk = 1; msk < 16; msk <<= 1)
#pragma unroll
        for (int i = 0; i < 4; i++) ss[i] += __shfl_xor(ss[i], msk);
    float scl[4];
#pragma unroll
    for (int i = 0; i < 4; i++) scl[i] = 1.f / fmaxf(sqrtf(ss[i]), 1e-12f);
#pragma unroll
    for (int t = 0; t < 13; t++) {
        int gn = t * 16 + l16;
        if (gn >= OD) continue;
#pragma unroll
        for (int i = 0; i < 4; i++) {
            int gm = orow + i;
            if (gm < M) outent[(size_t)gm * OD + gn] = acc[t][i] * scl[i];
        }
    }
}

// -------- generic MFMA GEMM (small R-sized matmuls); cs/co = C col-stride --
#define KPAD 48
template<bool BTr, typename AT, typename CT>
__global__ __launch_bounds__(256)
void gemm_mfma_k(const AT* __restrict__ A, int lda, const float* __restrict__ ascale,
                 const float* __restrict__ B, int ldb, int colOff,
                 CT* __restrict__ C, int ldc, int cs, int co,
                 int M, int Nc, int K)
{
    __shared__ __align__(16) __hip_bfloat16 As[64][KPAD];
    __shared__ __align__(16) __hip_bfloat16 Bs[64][KPAD];
    int tid  = threadIdx.x;
    int wave = tid >> 6, lane = tid & 63;
    int quad = lane >> 4, l16 = lane & 15;
    int n0 = blockIdx.x * 64, m0 = blockIdx.y * 64;
    f32x4 acc[4];
#pragma unroll
    for (int t = 0; t < 4; t++) acc[t] = (f32x4){0.f, 0.f, 0.f, 0.f};

    for (int k0 = 0; k0 < K; k0 += 32) {
        {
            int m = tid >> 2, kc = (tid & 3) * 8;
            int gm = m0 + m;
            float scale = (ascale && gm < M) ? ascale[gm] : 1.f;
#pragma unroll
            for (int j = 0; j < 8; j++) {
                int gk = k0 + kc + j;
                float v = 0.f;
                if (gm < M && gk < K) v = toF(A[(size_t)gm * lda + gk]) * scale;
                As[m][kc + j] = __float2bfloat16(v);
            }
        }
        if (BTr) {
            int n = tid >> 2, kc = (tid & 3) * 8;
            int gn = n0 + n;
#pragma unroll
            for (int j = 0; j < 8; j++) {
                int gk = k0 + kc + j;
                float v = 0.f;
                if (gn < Nc && gk < K) v = B[(size_t)gn * ldb + colOff + gk];
                Bs[n][kc + j] = __float2bfloat16(v);
            }
        } else {
            int n = tid & 63, kq = tid >> 6;
            int gn = n0 + n;
#pragma unroll
            for (int j = 0; j < 8; j++) {
                int gk = k0 + kq * 8 + j;
                float v = 0.f;
                if (gn < Nc && gk < K) v = B[(size_t)gk * ldb + gn];
                Bs[n][kq * 8 + j] = __float2bfloat16(v);
            }
        }
        __syncthreads();
        short8 a = *(const short8*)&As[wave * 16 + l16][quad * 8];
#pragma unroll
        for (int t = 0; t < 4; t++) {
            short8 b = *(const short8*)&Bs[t * 16 + l16][quad * 8];
            acc[t] = __builtin_amdgcn_mfma_f32_16x16x32_bf16(a, b, acc[t], 0, 0, 0);
        }
        __syncthreads();
    }
#pragma unroll
    for (int t = 0; t < 4; t++) {
        int gn = n0 + t * 16 + l16;
        if (gn >= Nc) continue;
#pragma unroll
        for (int i = 0; i < 4; i++) {
            int gm = m0 + wave * 16 + quad * 4 + i;
            if (gm < M) storeC(acc[t][i], &C[(size_t)gm * ldc + (size_t)gn * cs + co]);
        }
    }
}

// -------- row-dot (srel); ks = k-stride in mat, os/oo = output stride ------
template<typename T>
__global__ __launch_bounds__(256)
void rowdot_k(const T* __restrict__ mat, int ld, int coff, int ks,
              const float* __restrict__ vec,
              float* __restrict__ outp, int os, int oo, int M, int Dd)
{
    int wave = (blockIdx.x * blockDim.x + threadIdx.x) >> 6;
    int lane = threadIdx.x & 63;
    if (wave >= M) return;
    float s = 0.f;
    for (int k = lane; k < Dd; k += 64)
        s += toF(mat[(size_t)wave * ld + coff + (size_t)k * ks]) * vec[k];
    for (int o = 32; o > 0; o >>= 1) s += __shfl_down(s, o);
    if (lane == 0) outp[wave * os + oo] = s;
}

// -------- CSR build --------
__device__ inline void decode_edge(const int* __restrict__ el, int E,
                                   const int* __restrict__ etype,
                                   const int* __restrict__ tin, int e,
                                   int& dst, int& src, int& r1, int& r2)
{
    if (e < E) { dst = el[e]; src = el[E + e]; r1 = etype[e]; r2 = -1; }
    else {
        int j = e - E;
        dst = tin[j * 4 + 3]; src = tin[j * 4 + 0];
        r1 = tin[j * 4 + 1];  r2 = tin[j * 4 + 2];
    }
}

__global__ void hist_k(const int* __restrict__ el, int E, const int* __restrict__ etype,
                       const int* __restrict__ tin, int Etot, int* __restrict__ cnt)
{
    int e = blockIdx.x * blockDim.x + threadIdx.x;
    if (e >= Etot) return;
    int dst, src, r1, r2; decode_edge(el, E, etype, tin, e, dst, src, r1, r2);
    atomicAdd(&cnt[dst], 1);
}

__global__ __launch_bounds__(1024)
void scan1_k(const int* __restrict__ cnt, int* __restrict__ start,
             int* __restrict__ aux, int n)
{
    __shared__ int tmp[1024];
    int i = blockIdx.x * 1024 + threadIdx.x;
    int v = (i < n) ? cnt[i] : 0;
    tmp[threadIdx.x] = v;
    __syncthreads();
    for (int o = 1; o < 1024; o <<= 1) {
        int t = (threadIdx.x >= (unsigned)o) ? tmp[threadIdx.x - o] : 0;
        __syncthreads();
        tmp[threadIdx.x] += t;
        __syncthreads();
    }
    if (i < n) start[i] = tmp[threadIdx.x] - v;
    if (threadIdx.x == 1023) aux[blockIdx.x] = tmp[1023];
}

__global__ void scan2_k(int* __restrict__ aux, int nb)
{
    if (threadIdx.x == 0 && blockIdx.x == 0) {
        int s = 0;
        for (int i = 0; i < nb; i++) { int v = aux[i]; aux[i] = s; s += v; }
    }
}

__global__ __launch_bounds__(1024)
void scan3_k(int* __restrict__ start, const int* __restrict__ aux, int n, int Etot)
{
    int i = blockIdx.x * 1024 + threadIdx.x;
    if (i < n) start[i] += aux[blockIdx.x];
    if (i == 0) start[n] = Etot;
}

// csr entry: .x = src, .y = r1 | (r2s<<16), r2s==0xFFFF means "no r2"
__global__ void fill_k(const int* __restrict__ el, int E, const int* __restrict__ etype,
                       const int* __restrict__ tin, int Etot,
                       const int* __restrict__ start, int* __restrict__ fill,
                       int2* __restrict__ csr)
{
    int e = blockIdx.x * blockDim.x + threadIdx.x;
    if (e >= Etot) return;
    int dst, src, r1, r2; decode_edge(el, E, etype, tin, e, dst, src, r1, r2);
    int p = start[dst] + atomicAdd(&fill[dst], 1);
    unsigned r2s = (r2 >= 0) ? (unsigned)r2 : 0xFFFFu;
    csr[p] = make_int2(src, (int)((r2s << 16) | (unsigned)r1));
}

// -------- layer-1 gather: wave/dst, phase-split 4-edge blocks --------------
__global__ __launch_bounds__(256, 2)
void gather_l1_k(const int* __restrict__ start, const int2* __restrict__ csr,
                 const float* __restrict__ s1,        // [2][N] dst-side
                 const float* __restrict__ srel2,     // [R][2]
                 const __hip_bfloat16* __restrict__ pB,   // [N][PBS] interleaved
                 const float* __restrict__ rpf2,      // [R][100][2]
                 __hip_bfloat16* __restrict__ x1, int N)  // [N][KP]
{
    int n = (blockIdx.x * blockDim.x + threadIdx.x) >> 6;
    int lane = threadIdx.x & 63;
    if (n >= N) return;
    int b0 = start[n], b1 = start[n + 1];
    float s1h0 = s1[n], s1h1 = s1[N + n];
    float rs0 = 0.f, rs1 = 0.f;
    float2 acc0 = {0.f, 0.f};   // k0: (h0, h1)
    float2 acc1 = {0.f, 0.f};   // k1
    int k0 = lane;
    bool k1ok = lane < 36;
    int k1c = k1ok ? (lane + 64) : 0;
    const float2 z2 = {0.f, 0.f};

    for (int base = b0; base < b1; base += 4) {
        // ---- phase A: pure loads (wave-uniform branches; results stay live)
        unsigned pw0[4], pw1[4];
        float2 sA[4], q1a[4], q1b[4], q2a[4], q2b[4], sr1[4], sr2[4];
#pragma unroll
        for (int u = 0; u < 4; u++) {
            int id = base + u;
            if (id < b1) {
                int2 eg = csr[id];
                unsigned ey = (unsigned)eg.y;
                int r1 = (int)(ey & 0xFFFFu);
                unsigned r2u = ey >> 16;
                const __hip_bfloat16* rA = pB + (unsigned)((unsigned)eg.x * PBS);
                sA[u]  = *(const float2*)(rA + 200);
                pw0[u] = *(const unsigned*)(rA + 2 * k0);
                pw1[u] = *(const unsigned*)(rA + 2 * k1c);
                const float2* q1 = (const float2*)(rpf2 + (unsigned)r1 * 200);
                q1a[u] = q1[k0]; q1b[u] = q1[k1c];
                sr1[u] = *(const float2*)(srel2 + r1 * 2);
                if (r2u != 0xFFFFu) {
                    const float2* q2 = (const float2*)(rpf2 + r2u * 200);
                    q2a[u] = q2[k0]; q2b[u] = q2[k1c];
                    sr2[u] = *(const float2*)(srel2 + r2u * 2);
                } else {
                    q2a[u] = z2; q2b[u] = z2; sr2[u] = z2;
                }
            } else {
                pw0[u] = 0; pw1[u] = 0; sA[u] = z2;
                q1a[u] = z2; q1b[u] = z2; q2a[u] = z2; q2b[u] = z2;
                sr1[u] = z2; sr2[u] = z2;
            }
        }
        // ---- phase B: compute
#pragma unroll
        for (int u = 0; u < 4; u++) {
            bool val = (base + u) < b1;
            float z0 = s1h0 + sA[u].x + sr1[u].x + sr2[u].x;
            float z1 = s1h1 + sA[u].y + sr1[u].y + sr2[u].y;
            float e0 = expf(-(z0 > 0.f ? z0 : 0.2f * z0));
            float e1 = expf(-(z1 > 0.f ? z1 : 0.2f * z1));
            float w0 = val ? e0 : 0.f;
            float w1 = val ? e1 : 0.f;
            rs0 += w0; rs1 += w1;
            float v00 = bfLo(pw0[u]) + q1a[u].x + q2a[u].x;
            float v01 = bfHi(pw0[u]) + q1a[u].y + q2a[u].y;
            float v10 = bfLo(pw1[u]) + q1b[u].x + q2b[u].x;
            float v11 = bfHi(pw1[u]) + q1b[u].y + q2b[u].y;
            acc0.x += w0 * v00; acc0.y += w1 * v01;
            acc1.x += w0 * v10; acc1.y += w1 * v11;
        }
    }

    float i0 = rs0 > 0.f ? 1.f / rs0 : 0.f;
    float i1 = rs1 > 0.f ? 1.f / rs1 : 0.f;
    __hip_bfloat16* xr = x1 + (size_t)n * KP;
    float hp;
    hp = rs0 > 0.f ? toF(xr[k0]) + acc0.x * i0 : 0.f;
    xr[k0] = __float2bfloat16(hp > 0.f ? hp : expf(hp) - 1.f);
    hp = rs1 > 0.f ? toF(xr[100 + k0]) + acc0.y * i1 : 0.f;
    xr[100 + k0] = __float2bfloat16(hp > 0.f ? hp : expf(hp) - 1.f);
    if (k1ok) {
        int k1 = lane + 64;
        hp = rs0 > 0.f ? toF(xr[k1]) + acc1.x * i0 : 0.f;
        xr[k1] = __float2bfloat16(hp > 0.f ? hp : expf(hp) - 1.f);
        hp = rs1 > 0.f ? toF(xr[100 + k1]) + acc1.y * i1 : 0.f;
        xr[100 + k1] = __float2bfloat16(hp > 0.f ? hp : expf(hp) - 1.f);
    }
}

// -------- layer-2 gather: wave/dst, phase-split 4-edge blocks --------------
__global__ __launch_bounds__(256, 2)
void gather_l2_k(const int* __restrict__ start, const int2* __restrict__ csr,
                 const float* __restrict__ s1,
                 const float* __restrict__ srel,          // [R]
                 const __hip_bfloat16* __restrict__ x1A2, // [N][PBS] + s2 in pad
                 const float* __restrict__ rpf,           // [R][200]
                 const float* __restrict__ maskf,
                 float* __restrict__ outent, int N)       // [N][200], holds x1A1
{
    int n = (blockIdx.x * blockDim.x + threadIdx.x) >> 6;
    int lane = threadIdx.x & 63;
    if (n >= N) return;
    int b0 = start[n], b1 = start[n + 1];
    float s1n = s1[n];
    float rs = 0.f;
    float2 a0 = {0.f, 0.f};   // k = 2*lane, 2*lane+1
    float2 a1 = {0.f, 0.f};   // k = 128+2*lane, +1 (lane<36)
    int j0 = 2 * lane;
    bool j1ok = lane < 36;
    int j1 = j1ok ? (128 + 2 * lane) : 0;
    const float2 z2 = {0.f, 0.f};

    for (int base = b0; base < b1; base += 4) {
        // ---- phase A: pure loads
        unsigned xw0[4], xw1[4];
        float s2v[4], sra[4], srb[4];
        float2 q1a[4], q1b[4], q2a[4], q2b[4];
#pragma unroll
        for (int u = 0; u < 4; u++) {
            int id = base + u;
            if (id < b1) {
                int2 eg = csr[id];
                unsigned ey = (unsigned)eg.y;
                int r1 = (int)(ey & 0xFFFFu);
                unsigned r2u = ey >> 16;
                const __hip_bfloat16* xs = x1A2 + (unsigned)((unsigned)eg.x * PBS);
                s2v[u] = *(const float*)(xs + 200);
                xw0[u] = *(const unsigned*)(xs + j0);
                xw1[u] = *(const unsigned*)(xs + j1);
                const float* q1 = rpf + (unsigned)r1 * 200;
                q1a[u] = *(const float2*)(q1 + j0);
                q1b[u] = *(const float2*)(q1 + j1);
                sra[u] = srel[r1];
                if (r2u != 0xFFFFu) {
                    const float* q2 = rpf + r2u * 200;
                    q2a[u] = *(const float2*)(q2 + j0);
                    q2b[u] = *(const float2*)(q2 + j1);
                    srb[u] = srel[r2u];
                } else {
                    q2a[u] = z2; q2b[u] = z2; srb[u] = 0.f;
                }
            } else {
                xw0[u] = 0; xw1[u] = 0; s2v[u] = 0.f;
                q1a[u] = z2; q1b[u] = z2; q2a[u] = z2; q2b[u] = z2;
                sra[u] = 0.f; srb[u] = 0.f;
            }
        }
        // ---- phase B: compute
#pragma unroll
        for (int u = 0; u < 4; u++) {
            bool val = (base + u) < b1;
            float z = s1n + s2v[u] + sra[u] + srb[u];
            float e = expf(-(z > 0.f ? z : 0.2f * z));
            float w = val ? e : 0.f;
            rs += w;
            float v0x = bfLo(xw0[u]) + q1a[u].x + q2a[u].x;
            float v0y = bfHi(xw0[u]) + q1a[u].y + q2a[u].y;
            float v1x = bfLo(xw1[u]) + q1b[u].x + q2b[u].x;
            float v1y = bfHi(xw1[u]) + q1b[u].y + q2b[u].y;
            a0.x += w * v0x; a0.y += w * v0y;
            a1.x += w * v1x; a1.y += w * v1y;
        }
    }

    float inv = rs > 0.f ? 1.f / rs : 0.f;
    float mk = maskf[n];
    float* orow = outent + (size_t)n * 200;
    {
        float2 o = *(const float2*)(orow + j0);
        float hpx = rs > 0.f ? o.x + a0.x * inv : 0.f;
        float hpy = rs > 0.f ? o.y + a0.y * inv : 0.f;
        float2 r;
        r.x = mk * (hpx > 0.f ? hpx : expf(hpx) - 1.f);
        r.y = mk * (hpy > 0.f ? hpy : expf(hpy) - 1.f);
        *(float2*)(orow + j0) = r;
    }
    if (j1ok) {
        float2 o = *(const float2*)(orow + j1);
        float hpx = rs > 0.f ? o.x + a1.x * inv : 0.f;
        float hpy = rs > 0.f ? o.y + a1.y * inv : 0.f;
        float2 r;
        r.x = mk * (hpx > 0.f ? hpx : expf(hpx) - 1.f);
        r.y = mk * (hpy > 0.f ? hpy : expf(hpy) - 1.f);
        *(float2*)(orow + j1) = r;
    }
}

__global__ void scatter_mask_k(const int* __restrict__ batch, int NB,
                               float* __restrict__ masko)
{
    int i = blockIdx.x * blockDim.x + threadIdx.x;
    if (i >= NB) return;
    masko[batch[i]] = 1.0f;
}

extern "C" void kernel_launch(void* const* d_in, const int* in_sizes, int n_in,
                              void* d_out, int out_size, void* d_ws, size_t ws_size,
                              hipStream_t stream)
{
    const float* ent      = (const float*)d_in[0];
    const float* rel      = (const float*)d_in[1];
    const float* W_ent    = (const float*)d_in[2];
    const float* W_gat    = (const float*)d_in[3];
    const float* a_heads  = (const float*)d_in[4];
    const float* a2_heads = (const float*)d_in[5];
    const float* a_out    = (const float*)d_in[6];
    const float* a2_out   = (const float*)d_in[7];
    const int* batch = (const int*)d_in[8];
    const int* el    = (const int*)d_in[9];
    const int* etype = (const int*)d_in[10];
    const int* tin   = (const int*)d_in[11];

    const int N   = in_sizes[0] / DD;   // 50000
    const int R   = in_sizes[1] / DD;   // 500
    const int NB  = in_sizes[8];        // 20000
    const int E   = in_sizes[9] / 2;    // 150000
    const int ENH = in_sizes[11] / 4;   // 30000
    const int Etot = E + ENH;

    // ---- workspace ----
    char* ws = (char*)d_ws;
    size_t off = 0;
    auto take = [&](size_t bytes) { size_t o = off; off += (bytes + 255) & ~(size_t)255; return o; };
    size_t o_R1   = take((size_t)N * KP * 2);     // x1 bf16 [N][KP]
    size_t o_R2   = take((size_t)N * PBS * 2);    // pB [N][PBS]; later x1A2 [N][PBS]
    size_t o_rpf  = take((size_t)2 * R * 100 * 4);// rpf2 [R][100][2] / layer2 rpf [R][200]
    size_t o_bt1  = take((size_t)400 * KP * 2);
    size_t o_bt2  = take((size_t)400 * KP * 2);
    size_t o_btf  = take((size_t)208 * KP * 2);
    size_t o_nsc  = take((size_t)N * 4);
    size_t o_s1   = take((size_t)2 * N * 4);      // aliased by cnt during CSR build
    size_t o_srel = take((size_t)2 * R * 4);      // [R][2] layer1 / [R] layer2
    size_t o_csr  = take((size_t)Etot * 8);
    size_t o_str  = take((size_t)(N + 1) * 4);
    size_t o_aux  = take((size_t)64 * 4);

    __hip_bfloat16* x1   = (__hip_bfloat16*)(ws + o_R1);
    __hip_bfloat16* pB   = (__hip_bfloat16*)(ws + o_R2);
    __hip_bfloat16* x1A2 = (__hip_bfloat16*)(ws + o_R2);
    float* rpf2   = (float*)(ws + o_rpf);
    __hip_bfloat16* bt1 = (__hip_bfloat16*)(ws + o_bt1);
    __hip_bfloat16* bt2 = (__hip_bfloat16*)(ws + o_bt2);
    __hip_bfloat16* btf = (__hip_bfloat16*)(ws + o_btf);
    float* nscale = (float*)(ws + o_nsc);
    float* s1     = (float*)(ws + o_s1);
    float* srel2  = (float*)(ws + o_srel);
    int2*  csr    = (int2*)(ws + o_csr);
    int*   cnt    = (int*)(ws + o_s1);   // CSR-build scratch; dead before l1_both_k writes s1
    int*   startA = (int*)(ws + o_str);
    int*   aux    = (int*)(ws + o_aux);

    float* out       = (float*)d_out;
    float* out_ent   = out;                                     // [N,200]
    float* out_rel_o = out + (size_t)N * OD;                    // [500,200]
    float* out_mask  = out + (size_t)N * OD + (size_t)R * OD;   // [N]

    const int nblk = cdiv(N, 64);
    const int nbScan = cdiv(N, 1024);

    // A. prep: norms, B panels, x1 pad; out_rel GEMM
    rownorm_inv_k<<<cdiv(N, 4), 256, 0, stream>>>(ent, nscale, N, DD);
    prep_bt_l1<<<400, 256, 0, stream>>>(a_heads, bt1);
    prep_bt_l2<<<400, 256, 0, stream>>>(a_out, bt2);
    prep_bt_fin<<<208, 256, 0, stream>>>(W_ent, btf);
    hipMemsetAsync(x1, 0, (size_t)N * KP * 2, stream);
    gemm_mfma_k<false, float, float><<<dim3(cdiv(OD, 64), cdiv(R, 64)), 256, 0, stream>>>(
        rel, DD, nullptr, W_gat, OD, 0, out_rel_o, OD, 1, 0, R, OD, DD);

    // A2. CSR build (dst-grouped edge lists)
    hipMemsetAsync(cnt, 0, (size_t)N * 4, stream);
    hist_k<<<cdiv(Etot, 256), 256, 0, stream>>>(el, E, etype, tin, Etot, cnt);
    scan1_k<<<nbScan, 1024, 0, stream>>>(cnt, startA, aux, N);
    scan2_k<<<1, 64, 0, stream>>>(aux, nbScan);
    scan3_k<<<nbScan, 1024, 0, stream>>>(startA, aux, N, Etot);
    hipMemsetAsync(cnt, 0, (size_t)N * 4, stream);
    fill_k<<<cdiv(Etot, 256), 256, 0, stream>>>(el, E, etype, tin, Etot, startA, cnt, csr);

    // B. layer-1 projections (both heads) + rel projections + gather
    l1_both_k<<<nblk, 256, 0, stream>>>(ent, nscale, bt1, a2_heads, x1, pB, s1, N);
    for (int h = 0; h < 2; h++) {
        const float* ah  = a_heads + (size_t)h * NHID * 600;
        const float* a2h = a2_heads + (size_t)h * NHID;
        gemm_mfma_k<true, float, float><<<dim3(cdiv(NHID, 64), cdiv(R, 64)), 256, 0, stream>>>(
            rel, DD, nullptr, ah, 600, 400, rpf2, 200, 2, h, R, NHID, DD);
        rowdot_k<float><<<cdiv(R, 4), 256, 0, stream>>>(
            rpf2, 200, h, 2, a2h, srel2, 2, h, R, NHID);
    }
    gather_l1_k<<<cdiv(N, 4), 256, 0, stream>>>(
        startA, csr, s1, srel2, pB, rpf2, x1, N);
    // pB dead; R2 becomes x1A2.

    // C. layer-2 projection + rel side
    l2_proj_k<<<nblk, 256, 0, stream>>>(x1, bt2, a2_out, out_ent, x1A2, s1, N);
    gemm_mfma_k<true, float, float><<<dim3(cdiv(OD, 64), cdiv(R, 64)), 256, 0, stream>>>(
        out_rel_o, OD, nullptr, a_out, 600, 400, rpf2, OD, 1, 0, R, OD, OD);
    rowdot_k<float><<<cdiv(R, 4), 256, 0, stream>>>(rpf2, OD, 0, 1, a2_out, srel2, 1, 0, R, OD);

    // D. mask; layer-2 gather (fused combine, single 200-wide pass)
    hipMemsetAsync(out_mask, 0, (size_t)N * 4, stream);
    scatter_mask_k<<<cdiv(NB, 256), 256, 0, stream>>>(batch, NB, out_mask);
    gather_l2_k<<<cdiv(N, 4), 256, 0, stream>>>(
        startA, csr, s1, srel2, x1A2, rpf2, out_mask, out_ent, N);

    // E. fused final GEMM + l2norm
    final_mfma_k<<<nblk, 256, 0, stream>>>(ent, nscale, btf, out_ent, N);
}

// Round 5
// 515.309 us; speedup vs baseline: 1.1034x; 1.0399x over previous
//
#include <hip/hip_runtime.h>
#include <hip/hip_bf16.h>
#include <math.h>

// SpKBGAT: N=50000, D=200, R=500, NHID=100, H=2, OD=200, E=150000, ENH=30000.
// R13: two-phase gather. Phase A computes ALL per-edge scalars lane-parallel
// (lane e = edge b0+e): csr/s2/srel loads issue simultaneously (MLP=deg), the
// exp/leakyrelu/rowsum instruction stream is paid once per chunk not per edge.
// Phase B broadcasts w/src via v_readlane (uniform->SGPR addressing) and does
// only feature FMAs, with 4-edge-batched pB loads (8 dwords live: allocator-
// friendly, unlike R11/R12's failed 64-dword batches).
#define DD   200
#define NHID 100
#define OD   200
#define KP   224   // padded K (7 chunks of 32)
#define PBS  224   // padded row stride (bf16) for pB / x1A2: 448 B
                   // pB: [k][h0,h1] pairs k<100; bytes 400..407 = s2 floats
                   // x1A2: 200 contiguous feats; byte 400 = s2 float
#define LDSW 40    // LDS row stride in shorts (80 B)

typedef __attribute__((ext_vector_type(8))) short short8;
typedef __attribute__((ext_vector_type(4))) float f32x4;

static inline int cdiv(int a, int b) { return (a + b - 1) / b; }

__device__ inline float toF(float x) { return x; }
__device__ inline float toF(__hip_bfloat16 x) { return __bfloat162float(x); }
__device__ inline void storeC(float v, float* p) { *p = v; }
__device__ inline void storeC(float v, __hip_bfloat16* p) { *p = __float2bfloat16(v); }
__device__ inline short bf16s(float f) {
    __hip_bfloat16 h = __float2bfloat16(f);
    short s; __builtin_memcpy(&s, &h, 2); return s;
}
__device__ inline float bfLo(unsigned u) { return __uint_as_float(u << 16); }
__device__ inline float bfHi(unsigned u) { return __uint_as_float(u & 0xFFFF0000u); }
__device__ inline float readlaneF(float v, int l) {
    return __uint_as_float((unsigned)__builtin_amdgcn_readlane((int)__float_as_uint(v), l));
}

// -------- per-row inverse L2 norm (f32), wave per row --------
__global__ __launch_bounds__(256)
void rownorm_inv_k(const float* __restrict__ in, float* __restrict__ sc, int M, int Dd)
{
    int wave = (blockIdx.x * blockDim.x + threadIdx.x) >> 6;
    int lane = threadIdx.x & 63;
    if (wave >= M) return;
    float ss = 0.f;
    for (int k = lane; k < Dd; k += 64) {
        float x = in[(size_t)wave * Dd + k];
        ss += x * x;
    }
    for (int o = 32; o > 0; o >>= 1) ss += __shfl_down(ss, o);
    if (lane == 0) sc[wave] = 1.f / fmaxf(sqrtf(ss), 1e-12f);
}

// -------- B-panel prep: bf16 [col][KP], zero-padded --------
__global__ void prep_bt_l1(const float* __restrict__ ah, __hip_bfloat16* __restrict__ Bt)
{
    int c = blockIdx.x, k = threadIdx.x;
    if (k >= KP) return;
    int seg = c / 100, idx = c - seg * 100;
    int h = seg & 1, off = (seg >> 1) * 200;
    float v = (k < 200) ? ah[(size_t)(h * 100 + idx) * 600 + off + k] : 0.f;
    Bt[(size_t)c * KP + k] = __float2bfloat16(v);
}
__global__ void prep_bt_l2(const float* __restrict__ ao, __hip_bfloat16* __restrict__ Bt)
{
    int c = blockIdx.x, k = threadIdx.x;
    if (k >= KP) return;
    int row = (c < 200) ? c : c - 200;
    int off = (c < 200) ? 0 : 200;
    float v = (k < 200) ? ao[(size_t)row * 600 + off + k] : 0.f;
    Bt[(size_t)c * KP + k] = __float2bfloat16(v);
}
__global__ void prep_bt_fin(const float* __restrict__ W, __hip_bfloat16* __restrict__ Bt)
{
    int c = blockIdx.x, k = threadIdx.x;
    if (k >= KP) return;
    float v = (c < 200 && k < 200) ? W[(size_t)k * 200 + c] : 0.f;
    Bt[(size_t)c * KP + k] = __float2bfloat16(v);
}

// -------- layer-1 fused (both heads): 25 tiles = xa1_h0|xa1_h1|xa2_h0|xa2_h1
__global__ __launch_bounds__(256)
void l1_both_k(const float* __restrict__ ent, const float* __restrict__ nscale,
               const __hip_bfloat16* __restrict__ Bt,  // [400][KP]
               const float* __restrict__ a2h,          // [2][100]
               __hip_bfloat16* __restrict__ x1,        // [N][KP] (cols 0-199)
               __hip_bfloat16* __restrict__ pB,        // [N][PBS] interleaved + s2 pad
               float* __restrict__ s1,                 // [2][N]
               int M)
{
    __shared__ __align__(16) __hip_bfloat16 Bs[400 * LDSW];  // 32 KB
    int tid = threadIdx.x, wave = tid >> 6, lane = tid & 63;
    int quad = lane >> 4, l16 = lane & 15;
    int m0 = blockIdx.x * 64;
    int arow = m0 + wave * 16 + l16;
    bool rok = arow < M;
    float nsc = rok ? nscale[arow] : 0.f;
    const float* arp = ent + (size_t)arow * DD;

    f32x4 acc[25];
#pragma unroll
    for (int t = 0; t < 25; t++) acc[t] = (f32x4){0.f, 0.f, 0.f, 0.f};

    short8 stg[7];
#pragma unroll
    for (int i = 0; i < 7; i++) {
        int idx = tid + i * 256;
        if (idx < 1600) {
            int r = idx >> 2, c8 = idx & 3;
            stg[i] = *(const short8*)(Bt + (size_t)r * KP + c8 * 8);
        }
    }

    for (int ch = 0; ch < 7; ch++) {
#pragma unroll
        for (int i = 0; i < 7; i++) {
            int idx = tid + i * 256;
            if (idx < 1600) {
                int r = idx >> 2, c8 = idx & 3;
                *(short8*)(Bs + r * LDSW + c8 * 8) = stg[i];
            }
        }
        __syncthreads();
        if (ch < 6) {
            int kb2 = (ch + 1) * 32;
#pragma unroll
            for (int i = 0; i < 7; i++) {
                int idx = tid + i * 256;
                if (idx < 1600) {
                    int r = idx >> 2, c8 = idx & 3;
                    stg[i] = *(const short8*)(Bt + (size_t)r * KP + kb2 + c8 * 8);
                }
            }
        }
        int kb = ch * 32 + quad * 8;
        float av[8];
        if (rok && kb + 8 <= DD) {
            const float4* p = (const float4*)(arp + kb);
            float4 u0 = p[0], u1 = p[1];
            av[0] = u0.x; av[1] = u0.y; av[2] = u0.z; av[3] = u0.w;
            av[4] = u1.x; av[5] = u1.y; av[6] = u1.z; av[7] = u1.w;
        } else {
#pragma unroll
            for (int j = 0; j < 8; j++) av[j] = (rok && kb + j < DD) ? arp[kb + j] : 0.f;
        }
        short8 a;
#pragma unroll
        for (int j = 0; j < 8; j++) a[j] = bf16s(av[j] * nsc);
        const __hip_bfloat16* bp = Bs + (size_t)l16 * LDSW + quad * 8;
#pragma unroll
        for (int t = 0; t < 25; t++) {
            short8 b = *(const short8*)(bp + (size_t)t * 16 * LDSW);
            acc[t] = __builtin_amdgcn_mfma_f32_16x16x32_bf16(a, b, acc[t], 0, 0, 0);
        }
        __syncthreads();
    }

    int orow = m0 + wave * 16 + quad * 4;
    float d0[4] = {0,0,0,0}, d1[4] = {0,0,0,0}, d2[4] = {0,0,0,0}, d3[4] = {0,0,0,0};
#pragma unroll
    for (int t = 0; t < 25; t++) {
        int c = t * 16 + l16;
        int seg = c / 100, idx = c - seg * 100;
        float w = a2h[(seg & 1) * 100 + idx];
#pragma unroll
        for (int i = 0; i < 4; i++) {
            float v = acc[t][i];
            float vw = v * w;
            if (seg == 0) d0[i] += vw;
            else if (seg == 1) d1[i] += vw;
            else if (seg == 2) d2[i] += vw;
            else d3[i] += vw;
            int gm = orow + i;
            if (gm < M) {
                if (seg < 2) x1[(size_t)gm * KP + c] = __float2bfloat16(v);
                else pB[(size_t)gm * PBS + idx * 2 + (seg - 2)] = __float2bfloat16(v);
            }
        }
    }
#pragma unroll
    for (int msk = 1; msk < 16; msk <<= 1)
#pragma unroll
        for (int i = 0; i < 4; i++) {
            d0[i] += __shfl_xor(d0[i], msk);
            d1[i] += __shfl_xor(d1[i], msk);
            d2[i] += __shfl_xor(d2[i], msk);
            d3[i] += __shfl_xor(d3[i], msk);
        }
    if (l16 == 0)
#pragma unroll
        for (int i = 0; i < 4; i++) {
            int gm = orow + i;
            if (gm < M) {
                s1[gm] = d0[i]; s1[M + gm] = d1[i];
                float2 sv; sv.x = d2[i]; sv.y = d3[i];
                *(float2*)((char*)pB + (size_t)gm * (PBS * 2) + 400) = sv;
            }
        }
}

// -------- layer-2 fused: 25 tiles = x1A1 (f32 -> out_ent) | x1A2 (bf16) ----
__global__ __launch_bounds__(256)
void l2_proj_k(const __hip_bfloat16* __restrict__ x1,  // [N][KP]
               const __hip_bfloat16* __restrict__ Bt,  // [400][KP]
               const float* __restrict__ a2o,          // [200]
               float* __restrict__ x1A1,               // [N][200] (out_ent)
               __hip_bfloat16* __restrict__ x1A2,      // [N][PBS], s2 in pad
               float* __restrict__ s1, int M)
{
    __shared__ __align__(16) __hip_bfloat16 Bs[400 * LDSW];  // 32 KB
    int tid = threadIdx.x, wave = tid >> 6, lane = tid & 63;
    int quad = lane >> 4, l16 = lane & 15;
    int m0 = blockIdx.x * 64;
    int arow = m0 + wave * 16 + l16;
    bool rok = arow < M;
    const __hip_bfloat16* arp = x1 + (size_t)arow * KP;

    f32x4 acc[25];
#pragma unroll
    for (int t = 0; t < 25; t++) acc[t] = (f32x4){0.f, 0.f, 0.f, 0.f};

    short8 stg[7];
#pragma unroll
    for (int i = 0; i < 7; i++) {
        int idx = tid + i * 256;
        if (idx < 1600) {
            int r = idx >> 2, c8 = idx & 3;
            stg[i] = *(const short8*)(Bt + (size_t)r * KP + c8 * 8);
        }
    }

    for (int ch = 0; ch < 7; ch++) {
#pragma unroll
        for (int i = 0; i < 7; i++) {
            int idx = tid + i * 256;
            if (idx < 1600) {
                int r = idx >> 2, c8 = idx & 3;
                *(short8*)(Bs + r * LDSW + c8 * 8) = stg[i];
            }
        }
        __syncthreads();
        if (ch < 6) {
            int kb2 = (ch + 1) * 32;
#pragma unroll
            for (int i = 0; i < 7; i++) {
                int idx = tid + i * 256;
                if (idx < 1600) {
                    int r = idx >> 2, c8 = idx & 3;
                    stg[i] = *(const short8*)(Bt + (size_t)r * KP + kb2 + c8 * 8);
                }
            }
        }
        int kb = ch * 32 + quad * 8;
        short8 a = (short8){0,0,0,0,0,0,0,0};
        if (rok) a = *(const short8*)(arp + kb);
        const __hip_bfloat16* bp = Bs + (size_t)l16 * LDSW + quad * 8;
#pragma unroll
        for (int t = 0; t < 25; t++) {
            short8 b = *(const short8*)(bp + (size_t)t * 16 * LDSW);
            acc[t] = __builtin_amdgcn_mfma_f32_16x16x32_bf16(a, b, acc[t], 0, 0, 0);
        }
        __syncthreads();
    }

    int orow = m0 + wave * 16 + quad * 4;
    float dA[4] = {0,0,0,0}, dB[4] = {0,0,0,0};
#pragma unroll
    for (int t = 0; t < 25; t++) {
        int c = t * 16 + l16;
        bool first = c < 200;
        int cc = first ? c : c - 200;
        float w = a2o[cc];
#pragma unroll
        for (int i = 0; i < 4; i++) {
            float v = acc[t][i];
            int gm = orow + i;
            if (first) {
                dA[i] += v * w;
                if (gm < M) x1A1[(size_t)gm * OD + c] = v;
            } else {
                dB[i] += v * w;
                if (gm < M) x1A2[(size_t)gm * PBS + cc] = __float2bfloat16(v);
            }
        }
    }
#pragma unroll
    for (int msk = 1; msk < 16; msk <<= 1)
#pragma unroll
        for (int i = 0; i < 4; i++) {
            dA[i] += __shfl_xor(dA[i], msk);
            dB[i] += __shfl_xor(dB[i], msk);
        }
    if (l16 == 0)
#pragma unroll
        for (int i = 0; i < 4; i++) {
            int gm = orow + i;
            if (gm < M) {
                s1[gm] = dA[i];
                *(float*)((char*)x1A2 + (size_t)gm * (PBS * 2) + 400) = dB[i];
            }
        }
}

// -------- final: out_ent = l2norm(out_ent + (ent*nscale) @ W_ent) ---------
__global__ __launch_bounds__(256)
void final_mfma_k(const float* __restrict__ ent, const float* __restrict__ nscale,
                  const __hip_bfloat16* __restrict__ Bt,  // [208][KP]
                  float* __restrict__ outent, int M)
{
    __shared__ __align__(16) __hip_bfloat16 Bs[208 * LDSW];  // 16.6 KB
    int tid = threadIdx.x, wave = tid >> 6, lane = tid & 63;
    int quad = lane >> 4, l16 = lane & 15;
    int m0 = blockIdx.x * 64;
    int arow = m0 + wave * 16 + l16;
    bool rok = arow < M;
    float nsc = rok ? nscale[arow] : 0.f;
    const float* arp = ent + (size_t)arow * DD;

    f32x4 acc[13];
#pragma unroll
    for (int t = 0; t < 13; t++) acc[t] = (f32x4){0.f, 0.f, 0.f, 0.f};

    short8 stg[4];
#pragma unroll
    for (int i = 0; i < 4; i++) {
        int idx = tid + i * 256;
        if (idx < 832) {
            int r = idx >> 2, c8 = idx & 3;
            stg[i] = *(const short8*)(Bt + (size_t)r * KP + c8 * 8);
        }
    }

    for (int ch = 0; ch < 7; ch++) {
#pragma unroll
        for (int i = 0; i < 4; i++) {
            int idx = tid + i * 256;
            if (idx < 832) {
                int r = idx >> 2, c8 = idx & 3;
                *(short8*)(Bs + r * LDSW + c8 * 8) = stg[i];
            }
        }
        __syncthreads();
        if (ch < 6) {
            int kb2 = (ch + 1) * 32;
#pragma unroll
            for (int i = 0; i < 4; i++) {
                int idx = tid + i * 256;
                if (idx < 832) {
                    int r = idx >> 2, c8 = idx & 3;
                    stg[i] = *(const short8*)(Bt + (size_t)r * KP + kb2 + c8 * 8);
                }
            }
        }
        int kb = ch * 32 + quad * 8;
        float av[8];
        if (rok && kb + 8 <= DD) {
            const float4* p = (const float4*)(arp + kb);
            float4 u0 = p[0], u1 = p[1];
            av[0] = u0.x; av[1] = u0.y; av[2] = u0.z; av[3] = u0.w;
            av[4] = u1.x; av[5] = u1.y; av[6] = u1.z; av[7] = u1.w;
        } else {
#pragma unroll
            for (int j = 0; j < 8; j++) av[j] = (rok && kb + j < DD) ? arp[kb + j] : 0.f;
        }
        short8 a;
#pragma unroll
        for (int j = 0; j < 8; j++) a[j] = bf16s(av[j] * nsc);
        const __hip_bfloat16* bp = Bs + (size_t)l16 * LDSW + quad * 8;
#pragma unroll
        for (int t = 0; t < 13; t++) {
            short8 b = *(const short8*)(bp + (size_t)t * 16 * LDSW);
            acc[t] = __builtin_amdgcn_mfma_f32_16x16x32_bf16(a, b, acc[t], 0, 0, 0);
        }
        __syncthreads();
    }

    int orow = m0 + wave * 16 + quad * 4;
    float ss[4] = {0.f, 0.f, 0.f, 0.f};
#pragma unroll
    for (int t = 0; t < 13; t++) {
        int gn = t * 16 + l16;
#pragma unroll
        for (int i = 0; i < 4; i++) {
            int gm = orow + i;
            float v = 0.f;
            if (gn < OD && gm < M) v = acc[t][i] + outent[(size_t)gm * OD + gn];
            acc[t][i] = v;
            ss[i] += v * v;
        }
    }
#pragma unroll
    for (int msk = 1; msk < 16; msk <<= 1)
#pragma unroll
        for (int i = 0; i < 4; i++) ss[i] += __shfl_xor(ss[i], msk);
    float scl[4];
#pragma unroll
    for (int i = 0; i < 4; i++) scl[i] = 1.f / fmaxf(sqrtf(ss[i]), 1e-12f);
#pragma unroll
    for (int t = 0; t < 13; t++) {
        int gn = t * 16 + l16;
        if (gn >= OD) continue;
#pragma unroll
        for (int i = 0; i < 4; i++) {
            int gm = orow + i;
            if (gm < M) outent[(size_t)gm * OD + gn] = acc[t][i] * scl[i];
        }
    }
}

// -------- generic MFMA GEMM (small R-sized matmuls); cs/co = C col-stride --
#define KPAD 48
template<bool BTr, typename AT, typename CT>
__global__ __launch_bounds__(256)
void gemm_mfma_k(const AT* __restrict__ A, int lda, const float* __restrict__ ascale,
                 const float* __restrict__ B, int ldb, int colOff,
                 CT* __restrict__ C, int ldc, int cs, int co,
                 int M, int Nc, int K)
{
    __shared__ __align__(16) __hip_bfloat16 As[64][KPAD];
    __shared__ __align__(16) __hip_bfloat16 Bs[64][KPAD];
    int tid  = threadIdx.x;
    int wave = tid >> 6, lane = tid & 63;
    int quad = lane >> 4, l16 = lane & 15;
    int n0 = blockIdx.x * 64, m0 = blockIdx.y * 64;
    f32x4 acc[4];
#pragma unroll
    for (int t = 0; t < 4; t++) acc[t] = (f32x4){0.f, 0.f, 0.f, 0.f};

    for (int k0 = 0; k0 < K; k0 += 32) {
        {
            int m = tid >> 2, kc = (tid & 3) * 8;
            int gm = m0 + m;
            float scale = (ascale && gm < M) ? ascale[gm] : 1.f;
#pragma unroll
            for (int j = 0; j < 8; j++) {
                int gk = k0 + kc + j;
                float v = 0.f;
                if (gm < M && gk < K) v = toF(A[(size_t)gm * lda + gk]) * scale;
                As[m][kc + j] = __float2bfloat16(v);
            }
        }
        if (BTr) {
            int n = tid >> 2, kc = (tid & 3) * 8;
            int gn = n0 + n;
#pragma unroll
            for (int j = 0; j < 8; j++) {
                int gk = k0 + kc + j;
                float v = 0.f;
                if (gn < Nc && gk < K) v = B[(size_t)gn * ldb + colOff + gk];
                Bs[n][kc + j] = __float2bfloat16(v);
            }
        } else {
            int n = tid & 63, kq = tid >> 6;
            int gn = n0 + n;
#pragma unroll
            for (int j = 0; j < 8; j++) {
                int gk = k0 + kq * 8 + j;
                float v = 0.f;
                if (gn < Nc && gk < K) v = B[(size_t)gk * ldb + gn];
                Bs[n][kq * 8 + j] = __float2bfloat16(v);
            }
        }
        __syncthreads();
        short8 a = *(const short8*)&As[wave * 16 + l16][quad * 8];
#pragma unroll
        for (int t = 0; t < 4; t++) {
            short8 b = *(const short8*)&Bs[t * 16 + l16][quad * 8];
            acc[t] = __builtin_amdgcn_mfma_f32_16x16x32_bf16(a, b, acc[t], 0, 0, 0);
        }
        __syncthreads();
    }
#pragma unroll
    for (int t = 0; t < 4; t++) {
        int gn = n0 + t * 16 + l16;
        if (gn >= Nc) continue;
#pragma unroll
        for (int i = 0; i < 4; i++) {
            int gm = m0 + wave * 16 + quad * 4 + i;
            if (gm < M) storeC(acc[t][i], &C[(size_t)gm * ldc + (size_t)gn * cs + co]);
        }
    }
}

// -------- row-dot (srel); ks = k-stride in mat, os/oo = output stride ------
template<typename T>
__global__ __launch_bounds__(256)
void rowdot_k(const T* __restrict__ mat, int ld, int coff, int ks,
              const float* __restrict__ vec,
              float* __restrict__ outp, int os, int oo, int M, int Dd)
{
    int wave = (blockIdx.x * blockDim.x + threadIdx.x) >> 6;
    int lane = threadIdx.x & 63;
    if (wave >= M) return;
    float s = 0.f;
    for (int k = lane; k < Dd; k += 64)
        s += toF(mat[(size_t)wave * ld + coff + (size_t)k * ks]) * vec[k];
    for (int o = 32; o > 0; o >>= 1) s += __shfl_down(s, o);
    if (lane == 0) outp[wave * os + oo] = s;
}

// -------- CSR build --------
__device__ inline void decode_edge(const int* __restrict__ el, int E,
                                   const int* __restrict__ etype,
                                   const int* __restrict__ tin, int e,
                                   int& dst, int& src, int& r1, int& r2)
{
    if (e < E) { dst = el[e]; src = el[E + e]; r1 = etype[e]; r2 = -1; }
    else {
        int j = e - E;
        dst = tin[j * 4 + 3]; src = tin[j * 4 + 0];
        r1 = tin[j * 4 + 1];  r2 = tin[j * 4 + 2];
    }
}

__global__ void hist_k(const int* __restrict__ el, int E, const int* __restrict__ etype,
                       const int* __restrict__ tin, int Etot, int* __restrict__ cnt)
{
    int e = blockIdx.x * blockDim.x + threadIdx.x;
    if (e >= Etot) return;
    int dst, src, r1, r2; decode_edge(el, E, etype, tin, e, dst, src, r1, r2);
    atomicAdd(&cnt[dst], 1);
}

__global__ __launch_bounds__(1024)
void scan1_k(const int* __restrict__ cnt, int* __restrict__ start,
             int* __restrict__ aux, int n)
{
    __shared__ int tmp[1024];
    int i = blockIdx.x * 1024 + threadIdx.x;
    int v = (i < n) ? cnt[i] : 0;
    tmp[threadIdx.x] = v;
    __syncthreads();
    for (int o = 1; o < 1024; o <<= 1) {
        int t = (threadIdx.x >= (unsigned)o) ? tmp[threadIdx.x - o] : 0;
        __syncthreads();
        tmp[threadIdx.x] += t;
        __syncthreads();
    }
    if (i < n) start[i] = tmp[threadIdx.x] - v;
    if (threadIdx.x == 1023) aux[blockIdx.x] = tmp[1023];
}

__global__ void scan2_k(int* __restrict__ aux, int nb)
{
    if (threadIdx.x == 0 && blockIdx.x == 0) {
        int s = 0;
        for (int i = 0; i < nb; i++) { int v = aux[i]; aux[i] = s; s += v; }
    }
}

__global__ __launch_bounds__(1024)
void scan3_k(int* __restrict__ start, const int* __restrict__ aux, int n, int Etot)
{
    int i = blockIdx.x * 1024 + threadIdx.x;
    if (i < n) start[i] += aux[blockIdx.x];
    if (i == 0) start[n] = Etot;
}

// csr entry: .x = src, .y = r1 | (r2s<<16), r2s==0xFFFF means "no r2"
__global__ void fill_k(const int* __restrict__ el, int E, const int* __restrict__ etype,
                       const int* __restrict__ tin, int Etot,
                       const int* __restrict__ start, int* __restrict__ fill,
                       int2* __restrict__ csr)
{
    int e = blockIdx.x * blockDim.x + threadIdx.x;
    if (e >= Etot) return;
    int dst, src, r1, r2; decode_edge(el, E, etype, tin, e, dst, src, r1, r2);
    int p = start[dst] + atomicAdd(&fill[dst], 1);
    unsigned r2s = (r2 >= 0) ? (unsigned)r2 : 0xFFFFu;
    csr[p] = make_int2(src, (int)((r2s << 16) | (unsigned)r1));
}

// -------- layer-1 gather: wave/dst, two-phase (lane-parallel scalars) ------
__global__ __launch_bounds__(256)
void gather_l1_k(const int* __restrict__ start, const int2* __restrict__ csr,
                 const float* __restrict__ s1,        // [2][N] dst-side
                 const float* __restrict__ srel2,     // [R][2]
                 const __hip_bfloat16* __restrict__ pB,   // [N][PBS] interleaved
                 const float* __restrict__ rpf2,      // [R][100][2]
                 __hip_bfloat16* __restrict__ x1, int N)  // [N][KP]
{
    int n = (blockIdx.x * blockDim.x + threadIdx.x) >> 6;
    int lane = threadIdx.x & 63;
    if (n >= N) return;
    int b0 = __builtin_amdgcn_readfirstlane(start[n]);
    int b1 = __builtin_amdgcn_readfirstlane(start[n + 1]);
    float s1h0 = s1[n], s1h1 = s1[N + n];
    float rsl0 = 0.f, rsl1 = 0.f;        // per-lane partial rowsums
    float2 acc0 = {0.f, 0.f};            // k0: (h0, h1)
    float2 acc1 = {0.f, 0.f};            // k1
    int k0 = lane;
    bool k1ok = lane < 36;
    int k1c = k1ok ? (lane + 64) : 0;

    for (int c0 = b0; c0 < b1; c0 += 64) {
        int cnt = min(64, b1 - c0);
        // ---- phase A: lane e computes edge (c0+e)'s scalars; all loads in flight
        float w0 = 0.f, w1 = 0.f;
        int srcL = 0, eyL = 0;
        if (lane < cnt) {
            int2 eg = csr[c0 + lane];
            srcL = eg.x; eyL = eg.y;
            int r1 = eyL & 0xFFFF;
            unsigned r2u = (unsigned)eyL >> 16;
            float2 sA = *(const float2*)((const char*)pB + (size_t)(unsigned)srcL * (PBS * 2) + 400);
            float2 sr = *(const float2*)(srel2 + r1 * 2);
            float z0 = s1h0 + sA.x + sr.x;
            float z1 = s1h1 + sA.y + sr.y;
            if (r2u != 0xFFFFu) {
                float2 sr2v = *(const float2*)(srel2 + r2u * 2);
                z0 += sr2v.x; z1 += sr2v.y;
            }
            w0 = expf(-(z0 > 0.f ? z0 : 0.2f * z0));
            w1 = expf(-(z1 > 0.f ? z1 : 0.2f * z1));
            rsl0 += w0; rsl1 += w1;
        }
        // ---- phase B: per-edge feature FMA; 4-edge-batched pB loads
        for (int e0 = 0; e0 < cnt; e0 += 4) {
            int ec = min(4, cnt - e0);
            unsigned pw0[4], pw1[4];
#pragma unroll
            for (int u = 0; u < 4; u++) {
                if (u < ec) {
                    int s = __builtin_amdgcn_readlane(srcL, e0 + u);
                    const __hip_bfloat16* rA = pB + (size_t)(unsigned)s * PBS;
                    pw0[u] = *(const unsigned*)(rA + 2 * k0);
                    pw1[u] = *(const unsigned*)(rA + 2 * k1c);
                }
            }
#pragma unroll
            for (int u = 0; u < 4; u++) {
                if (u < ec) {
                    int ey = __builtin_amdgcn_readlane(eyL, e0 + u);
                    int r1 = ey & 0xFFFF;
                    unsigned r2u = (unsigned)ey >> 16;
                    float we0 = readlaneF(w0, e0 + u);
                    float we1 = readlaneF(w1, e0 + u);
                    const float2* q1 = (const float2*)(rpf2 + (unsigned)r1 * 200);
                    float2 q1a = q1[k0], q1b = q1[k1c];
                    float v00 = bfLo(pw0[u]) + q1a.x;
                    float v01 = bfHi(pw0[u]) + q1a.y;
                    float v10 = bfLo(pw1[u]) + q1b.x;
                    float v11 = bfHi(pw1[u]) + q1b.y;
                    if (r2u != 0xFFFFu) {
                        const float2* q2 = (const float2*)(rpf2 + r2u * 200);
                        float2 q2a = q2[k0], q2b = q2[k1c];
                        v00 += q2a.x; v01 += q2a.y;
                        v10 += q2b.x; v11 += q2b.y;
                    }
                    acc0.x += we0 * v00; acc0.y += we1 * v01;
                    acc1.x += we0 * v10; acc1.y += we1 * v11;
                }
            }
        }
    }

    // wave-reduce rowsums (butterfly -> all lanes)
#pragma unroll
    for (int o = 1; o < 64; o <<= 1) {
        rsl0 += __shfl_xor(rsl0, o);
        rsl1 += __shfl_xor(rsl1, o);
    }
    float i0 = rsl0 > 0.f ? 1.f / rsl0 : 0.f;
    float i1 = rsl1 > 0.f ? 1.f / rsl1 : 0.f;
    __hip_bfloat16* xr = x1 + (size_t)n * KP;
    float hp;
    hp = rsl0 > 0.f ? toF(xr[k0]) + acc0.x * i0 : 0.f;
    xr[k0] = __float2bfloat16(hp > 0.f ? hp : expf(hp) - 1.f);
    hp = rsl1 > 0.f ? toF(xr[100 + k0]) + acc0.y * i1 : 0.f;
    xr[100 + k0] = __float2bfloat16(hp > 0.f ? hp : expf(hp) - 1.f);
    if (k1ok) {
        int k1 = lane + 64;
        hp = rsl0 > 0.f ? toF(xr[k1]) + acc1.x * i0 : 0.f;
        xr[k1] = __float2bfloat16(hp > 0.f ? hp : expf(hp) - 1.f);
        hp = rsl1 > 0.f ? toF(xr[100 + k1]) + acc1.y * i1 : 0.f;
        xr[100 + k1] = __float2bfloat16(hp > 0.f ? hp : expf(hp) - 1.f);
    }
}

// -------- layer-2 gather: wave/dst, two-phase (lane-parallel scalars) ------
__global__ __launch_bounds__(256)
void gather_l2_k(const int* __restrict__ start, const int2* __restrict__ csr,
                 const float* __restrict__ s1,
                 const float* __restrict__ srel,          // [R]
                 const __hip_bfloat16* __restrict__ x1A2, // [N][PBS] + s2 in pad
                 const float* __restrict__ rpf,           // [R][200]
                 const float* __restrict__ maskf,
                 float* __restrict__ outent, int N)       // [N][200], holds x1A1
{
    int n = (blockIdx.x * blockDim.x + threadIdx.x) >> 6;
    int lane = threadIdx.x & 63;
    if (n >= N) return;
    int b0 = __builtin_amdgcn_readfirstlane(start[n]);
    int b1 = __builtin_amdgcn_readfirstlane(start[n + 1]);
    float s1n = s1[n];
    float rsl = 0.f;
    float2 a0 = {0.f, 0.f};   // k = 2*lane, 2*lane+1
    float2 a1 = {0.f, 0.f};   // k = 128+2*lane, +1 (lane<36)
    int j0 = 2 * lane;
    bool j1ok = lane < 36;
    int j1 = j1ok ? (128 + 2 * lane) : 0;

    for (int c0 = b0; c0 < b1; c0 += 64) {
        int cnt = min(64, b1 - c0);
        // ---- phase A: lane-parallel per-edge scalars
        float w = 0.f;
        int srcL = 0, eyL = 0;
        if (lane < cnt) {
            int2 eg = csr[c0 + lane];
            srcL = eg.x; eyL = eg.y;
            int r1 = eyL & 0xFFFF;
            unsigned r2u = (unsigned)eyL >> 16;
            float s2v = *(const float*)((const char*)x1A2 + (size_t)(unsigned)srcL * (PBS * 2) + 400);
            float sr = srel[r1];
            if (r2u != 0xFFFFu) sr += srel[r2u];
            float z = s1n + s2v + sr;
            w = expf(-(z > 0.f ? z : 0.2f * z));
            rsl += w;
        }
        // ---- phase B: per-edge feature FMA; 4-edge-batched feature loads
        for (int e0 = 0; e0 < cnt; e0 += 4) {
            int ec = min(4, cnt - e0);
            unsigned xw0[4], xw1[4];
#pragma unroll
            for (int u = 0; u < 4; u++) {
                if (u < ec) {
                    int s = __builtin_amdgcn_readlane(srcL, e0 + u);
                    const __hip_bfloat16* xs = x1A2 + (size_t)(unsigned)s * PBS;
                    xw0[u] = *(const unsigned*)(xs + j0);
                    xw1[u] = *(const unsigned*)(xs + j1);
                }
            }
#pragma unroll
            for (int u = 0; u < 4; u++) {
                if (u < ec) {
                    int ey = __builtin_amdgcn_readlane(eyL, e0 + u);
                    int r1 = ey & 0xFFFF;
                    unsigned r2u = (unsigned)ey >> 16;
                    float we = readlaneF(w, e0 + u);
                    const float* q1 = rpf + (unsigned)r1 * 200;
                    float2 q1a = *(const float2*)(q1 + j0);
                    float2 q1b = *(const float2*)(q1 + j1);
                    float v0x = bfLo(xw0[u]) + q1a.x;
                    float v0y = bfHi(xw0[u]) + q1a.y;
                    float v1x = bfLo(xw1[u]) + q1b.x;
                    float v1y = bfHi(xw1[u]) + q1b.y;
                    if (r2u != 0xFFFFu) {
                        const float* q2 = rpf + r2u * 200;
                        float2 q2a = *(const float2*)(q2 + j0);
                        float2 q2b = *(const float2*)(q2 + j1);
                        v0x += q2a.x; v0y += q2a.y;
                        v1x += q2b.x; v1y += q2b.y;
                    }
                    a0.x += we * v0x; a0.y += we * v0y;
                    a1.x += we * v1x; a1.y += we * v1y;
                }
            }
        }
    }

#pragma unroll
    for (int o = 1; o < 64; o <<= 1) rsl += __shfl_xor(rsl, o);
    float inv = rsl > 0.f ? 1.f / rsl : 0.f;
    float mk = maskf[n];
    float* orow = outent + (size_t)n * 200;
    {
        float2 o = *(const float2*)(orow + j0);
        float hpx = rsl > 0.f ? o.x + a0.x * inv : 0.f;
        float hpy = rsl > 0.f ? o.y + a0.y * inv : 0.f;
        float2 r;
        r.x = mk * (hpx > 0.f ? hpx : expf(hpx) - 1.f);
        r.y = mk * (hpy > 0.f ? hpy : expf(hpy) - 1.f);
        *(float2*)(orow + j0) = r;
    }
    if (j1ok) {
        float2 o = *(const float2*)(orow + j1);
        float hpx = rsl > 0.f ? o.x + a1.x * inv : 0.f;
        float hpy = rsl > 0.f ? o.y + a1.y * inv : 0.f;
        float2 r;
        r.x = mk * (hpx > 0.f ? hpx : expf(hpx) - 1.f);
        r.y = mk * (hpy > 0.f ? hpy : expf(hpy) - 1.f);
        *(float2*)(orow + j1) = r;
    }
}

__global__ void scatter_mask_k(const int* __restrict__ batch, int NB,
                               float* __restrict__ masko)
{
    int i = blockIdx.x * blockDim.x + threadIdx.x;
    if (i >= NB) return;
    masko[batch[i]] = 1.0f;
}

extern "C" void kernel_launch(void* const* d_in, const int* in_sizes, int n_in,
                              void* d_out, int out_size, void* d_ws, size_t ws_size,
                              hipStream_t stream)
{
    const float* ent      = (const float*)d_in[0];
    const float* rel      = (const float*)d_in[1];
    const float* W_ent    = (const float*)d_in[2];
    const float* W_gat    = (const float*)d_in[3];
    const float* a_heads  = (const float*)d_in[4];
    const float* a2_heads = (const float*)d_in[5];
    const float* a_out    = (const float*)d_in[6];
    const float* a2_out   = (const float*)d_in[7];
    const int* batch = (const int*)d_in[8];
    const int* el    = (const int*)d_in[9];
    const int* etype = (const int*)d_in[10];
    const int* tin   = (const int*)d_in[11];

    const int N   = in_sizes[0] / DD;   // 50000
    const int R   = in_sizes[1] / DD;   // 500
    const int NB  = in_sizes[8];        // 20000
    const int E   = in_sizes[9] / 2;    // 150000
    const int ENH = in_sizes[11] / 4;   // 30000
    const int Etot = E + ENH;

    // ---- workspace ----
    char* ws = (char*)d_ws;
    size_t off = 0;
    auto take = [&](size_t bytes) { size_t o = off; off += (bytes + 255) & ~(size_t)255; return o; };
    size_t o_R1   = take((size_t)N * KP * 2);     // x1 bf16 [N][KP]
    size_t o_R2   = take((size_t)N * PBS * 2);    // pB [N][PBS]; later x1A2 [N][PBS]
    size_t o_rpf  = take((size_t)2 * R * 100 * 4);// rpf2 [R][100][2] / layer2 rpf [R][200]
    size_t o_bt1  = take((size_t)400 * KP * 2);
    size_t o_bt2  = take((size_t)400 * KP * 2);
    size_t o_btf  = take((size_t)208 * KP * 2);
    size_t o_nsc  = take((size_t)N * 4);
    size_t o_s1   = take((size_t)2 * N * 4);      // aliased by cnt during CSR build
    size_t o_srel = take((size_t)2 * R * 4);      // [R][2] layer1 / [R] layer2
    size_t o_csr  = take((size_t)Etot * 8);
    size_t o_str  = take((size_t)(N + 1) * 4);
    size_t o_aux  = take((size_t)64 * 4);

    __hip_bfloat16* x1   = (__hip_bfloat16*)(ws + o_R1);
    __hip_bfloat16* pB   = (__hip_bfloat16*)(ws + o_R2);
    __hip_bfloat16* x1A2 = (__hip_bfloat16*)(ws + o_R2);
    float* rpf2   = (float*)(ws + o_rpf);
    __hip_bfloat16* bt1 = (__hip_bfloat16*)(ws + o_bt1);
    __hip_bfloat16* bt2 = (__hip_bfloat16*)(ws + o_bt2);
    __hip_bfloat16* btf = (__hip_bfloat16*)(ws + o_btf);
    float* nscale = (float*)(ws + o_nsc);
    float* s1     = (float*)(ws + o_s1);
    float* srel2  = (float*)(ws + o_srel);
    int2*  csr    = (int2*)(ws + o_csr);
    int*   cnt    = (int*)(ws + o_s1);   // CSR-build scratch; dead before l1_both_k writes s1
    int*   startA = (int*)(ws + o_str);
    int*   aux    = (int*)(ws + o_aux);

    float* out       = (float*)d_out;
    float* out_ent   = out;                                     // [N,200]
    float* out_rel_o = out + (size_t)N * OD;                    // [500,200]
    float* out_mask  = out + (size_t)N * OD + (size_t)R * OD;   // [N]

    const int nblk = cdiv(N, 64);
    const int nbScan = cdiv(N, 1024);

    // A. prep: norms, B panels, x1 pad; out_rel GEMM
    rownorm_inv_k<<<cdiv(N, 4), 256, 0, stream>>>(ent, nscale, N, DD);
    prep_bt_l1<<<400, 256, 0, stream>>>(a_heads, bt1);
    prep_bt_l2<<<400, 256, 0, stream>>>(a_out, bt2);
    prep_bt_fin<<<208, 256, 0, stream>>>(W_ent, btf);
    hipMemsetAsync(x1, 0, (size_t)N * KP * 2, stream);
    gemm_mfma_k<false, float, float><<<dim3(cdiv(OD, 64), cdiv(R, 64)), 256, 0, stream>>>(
        rel, DD, nullptr, W_gat, OD, 0, out_rel_o, OD, 1, 0, R, OD, DD);

    // A2. CSR build (dst-grouped edge lists)
    hipMemsetAsync(cnt, 0, (size_t)N * 4, stream);
    hist_k<<<cdiv(Etot, 256), 256, 0, stream>>>(el, E, etype, tin, Etot, cnt);
    scan1_k<<<nbScan, 1024, 0, stream>>>(cnt, startA, aux, N);
    scan2_k<<<1, 64, 0, stream>>>(aux, nbScan);
    scan3_k<<<nbScan, 1024, 0, stream>>>(startA, aux, N, Etot);
    hipMemsetAsync(cnt, 0, (size_t)N * 4, stream);
    fill_k<<<cdiv(Etot, 256), 256, 0, stream>>>(el, E, etype, tin, Etot, startA, cnt, csr);

    // B. layer-1 projections (both heads) + rel projections + gather
    l1_both_k<<<nblk, 256, 0, stream>>>(ent, nscale, bt1, a2_heads, x1, pB, s1, N);
    for (int h = 0; h < 2; h++) {
        const float* ah  = a_heads + (size_t)h * NHID * 600;
        const float* a2h = a2_heads + (size_t)h * NHID;
        gemm_mfma_k<true, float, float><<<dim3(cdiv(NHID, 64), cdiv(R, 64)), 256, 0, stream>>>(
            rel, DD, nullptr, ah, 600, 400, rpf2, 200, 2, h, R, NHID, DD);
        rowdot_k<float><<<cdiv(R, 4), 256, 0, stream>>>(
            rpf2, 200, h, 2, a2h, srel2, 2, h, R, NHID);
    }
    gather_l1_k<<<cdiv(N, 4), 256, 0, stream>>>(
        startA, csr, s1, srel2, pB, rpf2, x1, N);
    // pB dead; R2 becomes x1A2.

    // C. layer-2 projection + rel side
    l2_proj_k<<<nblk, 256, 0, stream>>>(x1, bt2, a2_out, out_ent, x1A2, s1, N);
    gemm_mfma_k<true, float, float><<<dim3(cdiv(OD, 64), cdiv(R, 64)), 256, 0, stream>>>(
        out_rel_o, OD, nullptr, a_out, 600, 400, rpf2, OD, 1, 0, R, OD, OD);
    rowdot_k<float><<<cdiv(R, 4), 256, 0, stream>>>(rpf2, OD, 0, 1, a2_out, srel2, 1, 0, R, OD);

    // D. mask; layer-2 gather (fused combine, single 200-wide pass)
    hipMemsetAsync(out_mask, 0, (size_t)N * 4, stream);
    scatter_mask_k<<<cdiv(NB, 256), 256, 0, stream>>>(batch, NB, out_mask);
    gather_l2_k<<<cdiv(N, 4), 256, 0, stream>>>(
        startA, csr, s1, srel2, x1A2, rpf2, out_mask, out_ent, N);

    // E. fused final GEMM + l2norm
    final_mfma_k<<<nblk, 256, 0, stream>>>(ent, nscale, btf, out_ent, N);
}